// Round 14
// baseline (980.530 us; speedup 1.0000x reference)
//
#include <hip/hip_runtime.h>
#include <math.h>

#define Bb 16
#define Nn 500
#define NT 501
#define Pp 100
#define Ee 128
#define Hh 8
#define Dd 16
#define Ff 512
#define Ll 6
#define Mtok (Bb*NT)   // 8016
#define PR (Bb*Pp)     // 1600
#define TJ 32          // attn_enc KV tile rows
#define SPLIT 4        // encoder KV-split (126,126,126,123)
#define KSEG 126
#define DSPLIT 16      // decoder KV-split
#define DSEG 32
#define ENCP (6*128*384)
#define DECP (128*256)
#define SNP 512        // padded score row stride
#define KP 36          // LDS bf16 row pitch (ushorts): b64-aligned reads, spread banks

typedef __attribute__((ext_vector_type(8))) short bf16x8;
typedef __attribute__((ext_vector_type(4))) float f32x4;

__device__ __forceinline__ unsigned short bfhi(float x){
  union { float f; unsigned u; } c; c.f = x; return (unsigned short)(c.u >> 16);
}
__device__ __forceinline__ float bff(unsigned short h){
  union { float f; unsigned u; } c; c.u = ((unsigned)h) << 16; return c.f;
}
__device__ __forceinline__ uint2 pack4(unsigned short a, unsigned short b,
                                       unsigned short c, unsigned short d){
  uint2 r; r.x = (unsigned)a | ((unsigned)b << 16);
  r.y = (unsigned)c | ((unsigned)d << 16); return r;
}

// ---------------------------------------------------------------- weight packing
__global__ __launch_bounds__(256) void pack_k(
    const float* __restrict__ ewq, const float* __restrict__ ewk, const float* __restrict__ ewv,
    const float* __restrict__ dwk, const float* __restrict__ dwv,
    float* __restrict__ encP, float* __restrict__ decP)
{
  int i = blockIdx.x*256 + threadIdx.x;
  if (i < ENCP) {
    int l = i / (128*384); int rem = i - l*128*384; int k = rem / 384; int n = rem - k*384;
    float v;
    if (n < 128)      v = ewq[((size_t)l*128 + k)*128 + n];
    else if (n < 256) v = ewk[((size_t)l*128 + k)*128 + (n-128)];
    else              v = ewv[((size_t)l*128 + k)*128 + (n-256)];
    encP[i] = v;
  } else {
    int j = i - ENCP;
    if (j < DECP) {
      int k = j >> 8; int n = j & 255;
      decP[j] = (n < 128) ? dwk[k*128 + n] : dwv[k*128 + (n-128)];
    }
  }
}

// ---------------------------------------------------------------- embed
__global__ __launch_bounds__(256) void embed_k(
    const float* __restrict__ depot_xy, const float* __restrict__ node_xy,
    const float* __restrict__ node_demand,
    const float* __restrict__ wD, const float* __restrict__ bD,
    const float* __restrict__ wN, const float* __restrict__ bN,
    float* __restrict__ x)
{
  int t = blockIdx.x*256 + threadIdx.x;
  if (t >= Mtok*Ee) return;
  int e   = t & (Ee-1);
  int tok = t >> 7;
  int b   = tok / NT;
  int n   = tok - b*NT;
  float v;
  if (n == 0) {
    v = depot_xy[b*2+0]*wD[0*Ee+e] + depot_xy[b*2+1]*wD[1*Ee+e] + bD[e];
  } else {
    int nn = n - 1;
    float c0 = node_xy[(b*Nn + nn)*2 + 0];
    float c1 = node_xy[(b*Nn + nn)*2 + 1];
    float c2 = node_demand[b*Nn + nn];
    v = c0*wN[0*Ee+e] + c1*wN[1*Ee+e] + c2*wN[2*Ee+e] + bN[e];
  }
  x[(size_t)tok*Ee + e] = v;
}

// ---------------------------------------------------------------- GEMM (split-bf16 MFMA)
// C[M,N] = A[M,K] @ W[K,N]  (+bias)(relu)(+res).  N%64==0, K%32==0.
// A*W ~= Ah*Wh + Ah*Wl + Al*Wh  (hi/lo bf16 truncation split, rel err ~2^-16).
// 64x64 tile, BK=32, 4 waves x 4 16x16x32 fragments, double-buffered LDS.
__global__ __launch_bounds__(256) void gemm_k(
    const float* __restrict__ A, const float* __restrict__ W,
    const float* __restrict__ bias, const float* __restrict__ res,
    float* __restrict__ C, int M, int N, int K, int relu)
{
  __shared__ __align__(16) unsigned short Ah[2][64][KP];
  __shared__ __align__(16) unsigned short Al[2][64][KP];
  __shared__ __align__(16) unsigned short Bh[2][64][KP];   // [n][k]
  __shared__ __align__(16) unsigned short Bl[2][64][KP];

  int tid = threadIdx.x;
  int m0 = blockIdx.x * 64, n0 = blockIdx.y * 64;
  int wvid = tid >> 6;            // wave 0..3 -> M rows [wvid*16, +16)
  int lane = tid & 63;
  int lrow = lane & 15;
  int lk8  = (lane >> 4) * 8;

  f32x4 acc0 = {0.f,0.f,0.f,0.f}, acc1 = acc0, acc2 = acc0, acc3 = acc0;

  int ar = tid >> 2;              // 0..63 A row
  int ac = (tid & 3) << 2;        // k 0,4,8,12
  int wr = tid >> 4;              // 0..15 W k-row
  int wc = (tid & 15) << 2;       // n 0..60

  const float* Ap = A + (size_t)(m0 + ar)*K + ac;
  const float* Wp = W + (size_t)wr*N + n0 + wc;
  bool aok = (m0 + ar) < M;

  float4 zz = make_float4(0.f,0.f,0.f,0.f);
  float4 av0 = aok ? *(const float4*)(Ap)      : zz;
  float4 av1 = aok ? *(const float4*)(Ap + 16) : zz;
  float4 wv0 = *(const float4*)(Wp);
  float4 wv1 = *(const float4*)(Wp + (size_t)16*N);

  int nk = K >> 5;
  for (int t = 0; t < nk; ++t) {
    int cur = t & 1;
    // ---- stage A (hi/lo, row-major [m][k]) ----
    {
      unsigned short h0=bfhi(av0.x), h1=bfhi(av0.y), h2=bfhi(av0.z), h3=bfhi(av0.w);
      unsigned short l0=bfhi(av0.x-bff(h0)), l1=bfhi(av0.y-bff(h1)),
                     l2=bfhi(av0.z-bff(h2)), l3=bfhi(av0.w-bff(h3));
      *(uint2*)&Ah[cur][ar][ac] = pack4(h0,h1,h2,h3);
      *(uint2*)&Al[cur][ar][ac] = pack4(l0,l1,l2,l3);
      h0=bfhi(av1.x); h1=bfhi(av1.y); h2=bfhi(av1.z); h3=bfhi(av1.w);
      l0=bfhi(av1.x-bff(h0)); l1=bfhi(av1.y-bff(h1));
      l2=bfhi(av1.z-bff(h2)); l3=bfhi(av1.w-bff(h3));
      *(uint2*)&Ah[cur][ar][ac+16] = pack4(h0,h1,h2,h3);
      *(uint2*)&Al[cur][ar][ac+16] = pack4(l0,l1,l2,l3);
    }
    // ---- stage W transposed (hi/lo, [n][k]) ----
    {
      float w4[4] = {wv0.x, wv0.y, wv0.z, wv0.w};
      #pragma unroll
      for (int i=0;i<4;i++){
        unsigned short h = bfhi(w4[i]);
        Bh[cur][wc+i][wr] = h;
        Bl[cur][wc+i][wr] = bfhi(w4[i] - bff(h));
      }
      float w5[4] = {wv1.x, wv1.y, wv1.z, wv1.w};
      #pragma unroll
      for (int i=0;i<4;i++){
        unsigned short h = bfhi(w5[i]);
        Bh[cur][wc+i][wr+16] = h;
        Bl[cur][wc+i][wr+16] = bfhi(w5[i] - bff(h));
      }
    }
    __syncthreads();
    if (t+1 < nk) {
      av0 = aok ? *(const float4*)(Ap + (size_t)(t+1)*32)      : zz;
      av1 = aok ? *(const float4*)(Ap + (size_t)(t+1)*32 + 16) : zz;
      wv0 = *(const float4*)(Wp + (size_t)(t+1)*32*N);
      wv1 = *(const float4*)(Wp + ((size_t)(t+1)*32 + 16)*N);
    }
    // ---- compute ----
    union FR { bf16x8 v; uint2 u[2]; };
    FR ah, al;
    ah.u[0] = *(const uint2*)&Ah[cur][wvid*16 + lrow][lk8];
    ah.u[1] = *(const uint2*)&Ah[cur][wvid*16 + lrow][lk8+4];
    al.u[0] = *(const uint2*)&Al[cur][wvid*16 + lrow][lk8];
    al.u[1] = *(const uint2*)&Al[cur][wvid*16 + lrow][lk8+4];
    #define DOFRAG(f, accv) { \
      FR bh, bl; \
      bh.u[0] = *(const uint2*)&Bh[cur][(f)*16 + lrow][lk8]; \
      bh.u[1] = *(const uint2*)&Bh[cur][(f)*16 + lrow][lk8+4]; \
      bl.u[0] = *(const uint2*)&Bl[cur][(f)*16 + lrow][lk8]; \
      bl.u[1] = *(const uint2*)&Bl[cur][(f)*16 + lrow][lk8+4]; \
      accv = __builtin_amdgcn_mfma_f32_16x16x32_bf16(ah.v, bh.v, accv, 0,0,0); \
      accv = __builtin_amdgcn_mfma_f32_16x16x32_bf16(ah.v, bl.v, accv, 0,0,0); \
      accv = __builtin_amdgcn_mfma_f32_16x16x32_bf16(al.v, bh.v, accv, 0,0,0); \
    }
    DOFRAG(0, acc0); DOFRAG(1, acc1); DOFRAG(2, acc2); DOFRAG(3, acc3);
    #undef DOFRAG
  }

  // ---- epilogue: D[row=(lane>>4)*4+j][col=lane&15] per fragment ----
  int crow0 = m0 + wvid*16 + (lane >> 4)*4;
  int col0  = n0 + lrow;
  #define WRFRAG(f, accv) { \
    int col = col0 + (f)*16; \
    float bvs = bias ? bias[col] : 0.f; \
    _Pragma("unroll") \
    for (int j=0;j<4;j++){ \
      int row = crow0 + j; \
      if (row < M) { \
        float v = accv[j] + bvs; \
        if (relu) v = fmaxf(v, 0.f); \
        if (res) v += res[(size_t)row*N + col]; \
        C[(size_t)row*N + col] = v; \
      } \
    } \
  }
  WRFRAG(0, acc0); WRFRAG(1, acc1); WRFRAG(2, acc2); WRFRAG(3, acc3);
  #undef WRFRAG
}

// ---------------------------------------------------------------- attention
__device__ __forceinline__ float dot4(float4 a, float4 b){
  return fmaf(a.x,b.x, fmaf(a.y,b.y, fmaf(a.z,b.z, a.w*b.w)));
}

// encoder self-attention v5: 256 threads, 2 queries/thread (tid, tid+256),
// one block covers all 501 queries of (b,h,s). Zero-conflict staging.
__global__ __launch_bounds__(256, 1) void attn_enc_k(
    const float* __restrict__ QKV, float* __restrict__ part_o,
    float* __restrict__ part_l)
{
  int blk = blockIdx.x;            // bh*SPLIT + s
  int s  = blk % SPLIT;
  int bh = blk / SPLIT;
  int h  = bh & (Hh-1);
  int b  = bh >> 3;
  int tid = threadIdx.x;
  int p0 = tid;
  int p1 = tid + 256;
  const int klo = s*KSEG;
  int kseg = NT - klo; if (kseg > KSEG) kseg = KSEG;

  __shared__ __align__(16) float4 Ks[2][TJ][4];
  __shared__ __align__(16) float4 Vs[2][TJ][4];

  int row = (tid >> 2) & 31;
  int lc  = tid & 3;
  bool isV = tid >= 128;
  const int kvoff = isV ? 256 : 128;

  bool vbq = p1 < NT;

  const float4* qp0 = (const float4*)(QKV + ((size_t)(b*NT + p0))*384 + h*Dd);
  float4 qa0=qp0[0], qa1=qp0[1], qa2=qp0[2], qa3=qp0[3];
  float4 qb0,qb1,qb2,qb3;
  if (vbq) {
    const float4* qp1 = (const float4*)(QKV + ((size_t)(b*NT + p1))*384 + h*Dd);
    qb0=qp1[0]; qb1=qp1[1]; qb2=qp1[2]; qb3=qp1[3];
  } else {
    qb0=qb1=qb2=qb3=make_float4(0,0,0,0);
  }

  if (row < kseg) {
    float4 v = *((const float4*)(QKV + ((size_t)(b*NT + klo + row))*384 + kvoff + h*Dd) + lc);
    if (isV) Vs[0][row][lc] = v; else Ks[0][row][lc] = v;
  }
  __syncthreads();

  float lA = 0.f, lB = 0.f;
  float4 oA0=make_float4(0,0,0,0), oA1=oA0, oA2=oA0, oA3=oA0;
  float4 oB0=oA0, oB1=oA0, oB2=oA0, oB3=oA0;
  const int ntiles = (kseg + TJ - 1)/TJ;
  int buf = 0;

  for (int t = 0; t < ntiles; ++t) {
    int j0 = t*TJ;
    if (t+1 < ntiles) {
      int jj = j0 + TJ + row;
      if (jj < kseg) {
        float4 v = *((const float4*)(QKV + ((size_t)(b*NT + klo + jj))*384 + kvoff + h*Dd) + lc);
        if (isV) Vs[buf^1][row][lc] = v; else Ks[buf^1][row][lc] = v;
      }
    }
    int jend = kseg - j0; if (jend > TJ) jend = TJ;

    #pragma unroll 2
    for (int jj = 0; jj < jend; ++jj) {
      float4 k0=Ks[buf][jj][0], k1=Ks[buf][jj][1], k2=Ks[buf][jj][2], k3=Ks[buf][jj][3];
      float sA = (dot4(qa0,k0)+dot4(qa1,k1)) + (dot4(qa2,k2)+dot4(qa3,k3));
      float sB = (dot4(qb0,k0)+dot4(qb1,k1)) + (dot4(qb2,k2)+dot4(qb3,k3));
      float wA = __expf(sA*0.25f);
      float wB = __expf(sB*0.25f);
      lA += wA; lB += wB;
      float4 v0=Vs[buf][jj][0], v1=Vs[buf][jj][1], v2=Vs[buf][jj][2], v3=Vs[buf][jj][3];
      oA0.x=fmaf(wA,v0.x,oA0.x); oA0.y=fmaf(wA,v0.y,oA0.y); oA0.z=fmaf(wA,v0.z,oA0.z); oA0.w=fmaf(wA,v0.w,oA0.w);
      oA1.x=fmaf(wA,v1.x,oA1.x); oA1.y=fmaf(wA,v1.y,oA1.y); oA1.z=fmaf(wA,v1.z,oA1.z); oA1.w=fmaf(wA,v1.w,oA1.w);
      oA2.x=fmaf(wA,v2.x,oA2.x); oA2.y=fmaf(wA,v2.y,oA2.y); oA2.z=fmaf(wA,v2.z,oA2.z); oA2.w=fmaf(wA,v2.w,oA2.w);
      oA3.x=fmaf(wA,v3.x,oA3.x); oA3.y=fmaf(wA,v3.y,oA3.y); oA3.z=fmaf(wA,v3.z,oA3.z); oA3.w=fmaf(wA,v3.w,oA3.w);
      oB0.x=fmaf(wB,v0.x,oB0.x); oB0.y=fmaf(wB,v0.y,oB0.y); oB0.z=fmaf(wB,v0.z,oB0.z); oB0.w=fmaf(wB,v0.w,oB0.w);
      oB1.x=fmaf(wB,v1.x,oB1.x); oB1.y=fmaf(wB,v1.y,oB1.y); oB1.z=fmaf(wB,v1.z,oB1.z); oB1.w=fmaf(wB,v1.w,oB1.w);
      oB2.x=fmaf(wB,v2.x,oB2.x); oB2.y=fmaf(wB,v2.y,oB2.y); oB2.z=fmaf(wB,v2.z,oB2.z); oB2.w=fmaf(wB,v2.w,oB2.w);
      oB3.x=fmaf(wB,v3.x,oB3.x); oB3.y=fmaf(wB,v3.y,oB3.y); oB3.z=fmaf(wB,v3.z,oB3.z); oB3.w=fmaf(wB,v3.w,oB3.w);
    }
    __syncthreads();
    buf ^= 1;
  }

  size_t r0 = ((size_t)s*128 + bh)*NT + p0;
  float4* po0 = (float4*)(part_o + r0*16);
  po0[0]=oA0; po0[1]=oA1; po0[2]=oA2; po0[3]=oA3;
  part_l[r0] = lA;
  if (vbq) {
    size_t r1 = ((size_t)s*128 + bh)*NT + p1;
    float4* po1 = (float4*)(part_o + r1*16);
    po1[0]=oB0; po1[1]=oB1; po1[2]=oB2; po1[3]=oB3;
    part_l[r1] = lB;
  }
}

// comb GEMM: C[Mtok][128] = combine(part)[Mtok][128] @ W + bias + res(xb).
__global__ __launch_bounds__(256) void comb_gemm_k(
    const float* __restrict__ part_o, const float* __restrict__ part_l,
    const float* __restrict__ W, const float* __restrict__ bias,
    const float* __restrict__ res, float* __restrict__ C)
{
  __shared__ __align__(16) float As[2][16][68];
  __shared__ __align__(16) float Bs[2][16][68];
  int tid = threadIdx.x;
  int tx = tid & 15, ty = tid >> 4;
  int m0 = blockIdx.x * 64, n0 = blockIdx.y * 64;
  float acc[4][4];
  #pragma unroll
  for (int i=0;i<4;i++)
    #pragma unroll
    for (int j=0;j<4;j++) acc[i][j] = 0.f;

  int ar = tid >> 2;
  int ak = (tid & 3) << 2;
  int br = tid >> 4;
  int bc = (tid & 15) << 2;

  int row = m0 + ar;
  bool aok = row < Mtok;
  int tok = aok ? row : 0;
  int bb = tok / NT;
  int p  = tok - bb*NT;
  const size_t pbase = ((size_t)(bb*8))*NT + p;

  const float* Wp = W + (size_t)br*Ee + n0 + bc;

  #define LOADA(t, dst) { \
    float4 o4 = make_float4(0.f,0.f,0.f,0.f); float l = 0.f; \
    _Pragma("unroll") \
    for (int s=0;s<SPLIT;s++){ \
      size_t idx = (size_t)s*((size_t)128*NT) + pbase + (size_t)(t)*NT; \
      float4 v = *(const float4*)(part_o + idx*16 + ak); \
      o4.x+=v.x; o4.y+=v.y; o4.z+=v.z; o4.w+=v.w; \
      l += part_l[idx]; \
    } \
    float inv = aok ? 1.f/l : 0.f; \
    dst = make_float4(o4.x*inv, o4.y*inv, o4.z*inv, o4.w*inv); \
  }

  float4 av; LOADA(0, av);
  float4 wv = *(const float4*)(Wp);

  for (int t = 0; t < 8; ++t) {
    int cur = t & 1;
    As[cur][ak+0][ar] = av.x; As[cur][ak+1][ar] = av.y;
    As[cur][ak+2][ar] = av.z; As[cur][ak+3][ar] = av.w;
    *(float4*)(&Bs[cur][br][bc]) = wv;
    __syncthreads();
    if (t+1 < 8) {
      LOADA(t+1, av);
      wv = *(const float4*)(Wp + (size_t)(t+1)*16*Ee);
    }
    #pragma unroll
    for (int k=0;k<16;k++){
      float4 a4 = *(const float4*)(&As[cur][k][ty*4]);
      float4 b4 = *(const float4*)(&Bs[cur][k][tx*4]);
      float avv[4] = {a4.x,a4.y,a4.z,a4.w};
      float bvv[4] = {b4.x,b4.y,b4.z,b4.w};
      #pragma unroll
      for (int i=0;i<4;i++)
        #pragma unroll
        for (int j=0;j<4;j++)
          acc[i][j] = fmaf(avv[i], bvv[j], acc[i][j]);
    }
  }
  #undef LOADA

  float4 bv = *(const float4*)(bias + n0 + tx*4);
  #pragma unroll
  for (int i=0;i<4;i++){
    int orow = m0 + ty*4 + i;
    if (orow >= Mtok) continue;
    float4 o;
    float4 rv = *(const float4*)(res + (size_t)orow*Ee + n0 + tx*4);
    o.x = acc[i][0] + bv.x + rv.x; o.y = acc[i][1] + bv.y + rv.y;
    o.z = acc[i][2] + bv.z + rv.z; o.w = acc[i][3] + bv.w + rv.w;
    *(float4*)(C + (size_t)orow*Ee + n0 + tx*4) = o;
  }
}

// decoder cross-attention: LDS-staged broadcast, DSPLIT=16 segments of 32.
__global__ __launch_bounds__(128) void attn_dec_k(
    const float* __restrict__ Q, const float* __restrict__ KV,
    const float* __restrict__ mask,
    float* __restrict__ part_o, float* __restrict__ part_l)
{
  int blk = blockIdx.x;
  int s  = blk & (DSPLIT-1);
  int bh = blk >> 4;
  int h  = bh & (Hh-1);
  int b  = bh >> 3;
  int klo = s*DSEG;
  int kn  = NT - klo; if (kn > DSEG) kn = DSEG;

  __shared__ __align__(16) float4 Ks[DSEG][4];
  __shared__ __align__(16) float4 Vs[DSEG][4];

  int tid = threadIdx.x;
  for (int i = tid; i < kn*8; i += 128) {
    int row  = i >> 3;
    int q8   = i & 7;
    int quad = q8 & 3;
    int isv  = q8 >> 2;
    float4 v = *(const float4*)(KV + ((size_t)(b*NT + klo + row))*256 + isv*128 + h*Dd + quad*4);
    if (isv) Vs[row][quad] = v; else Ks[row][quad] = v;
  }
  __syncthreads();

  int p = tid;
  if (p >= Pp) return;
  int r = b*Pp + p;
  const float4* qp = (const float4*)(Q + (size_t)r*Ee + h*Dd);
  float4 qa=qp[0], qb=qp[1], qc=qp[2], qd=qp[3];
  const float* mrow = mask + (size_t)r*NT + klo;

  float l = 0.f;
  float4 o0=make_float4(0,0,0,0), o1=o0, o2=o0, o3=o0;
  for (int j=0;j<kn;++j){
    float sc = (dot4(qa,Ks[j][0])+dot4(qb,Ks[j][1])) + (dot4(qc,Ks[j][2])+dot4(qd,Ks[j][3]));
    float w = __expf(sc*0.25f + mrow[j]);
    l += w;
    float4 v0=Vs[j][0],v1=Vs[j][1],v2=Vs[j][2],v3=Vs[j][3];
    o0.x=fmaf(w,v0.x,o0.x); o0.y=fmaf(w,v0.y,o0.y); o0.z=fmaf(w,v0.z,o0.z); o0.w=fmaf(w,v0.w,o0.w);
    o1.x=fmaf(w,v1.x,o1.x); o1.y=fmaf(w,v1.y,o1.y); o1.z=fmaf(w,v1.z,o1.z); o1.w=fmaf(w,v1.w,o1.w);
    o2.x=fmaf(w,v2.x,o2.x); o2.y=fmaf(w,v2.y,o2.y); o2.z=fmaf(w,v2.z,o2.z); o2.w=fmaf(w,v2.w,o2.w);
    o3.x=fmaf(w,v3.x,o3.x); o3.y=fmaf(w,v3.y,o3.y); o3.z=fmaf(w,v3.z,o3.z); o3.w=fmaf(w,v3.w,o3.w);
  }

  size_t rb = ((size_t)s*PR + r)*Hh + h;
  float4* po = (float4*)(part_o + rb*16);
  po[0]=o0; po[1]=o1; po[2]=o2; po[3]=o3;
  part_l[rb] = l;
}

// ---------------------------------------------------------------- decoder small ops
__global__ __launch_bounds__(128) void decq_k(
    const float* __restrict__ x, const int* __restrict__ cur,
    const float* __restrict__ loadv, const float* __restrict__ Wq,
    float* __restrict__ q, float* __restrict__ encl)
{
  __shared__ float row[Ee];
  int r = blockIdx.x, e = threadIdx.x;
  int b = r / Pp;
  int node = cur[r];
  float xv = x[((size_t)(b*NT + node))*Ee + e];
  encl[(size_t)r*Ee + e] = xv;
  row[e] = xv;
  __syncthreads();
  float acc = 0.f;
  #pragma unroll 4
  for (int k=0;k<Ee;k++) acc = fmaf(row[k], Wq[k*128 + e], acc);
  acc = fmaf(loadv[r], Wq[Ee*128 + e], acc);
  q[(size_t)r*128 + e] = acc;
}

__global__ __launch_bounds__(128) void dec_comb_k(
    const float* __restrict__ dpart_o, const float* __restrict__ dpart_l,
    const float* __restrict__ W, const float* __restrict__ bias,
    const float* __restrict__ encl, const float* __restrict__ loadv,
    const float* __restrict__ capw, float* __restrict__ mh)
{
  __shared__ float row[Ee];
  int r = blockIdx.x, e = threadIdx.x;
  int h = e >> 4, d = e & 15;
  const size_t S = (size_t)PR*Hh;
  size_t rb = (size_t)r*Hh + h;
  float L = 0.f, o = 0.f;
  #pragma unroll
  for (int s=0;s<DSPLIT;s++){
    L += dpart_l[(size_t)s*S + rb];
    o += dpart_o[((size_t)s*S + rb)*16 + d];
  }
  row[e] = o / L;
  __syncthreads();
  float acc = 0.f;
  #pragma unroll 4
  for (int k=0;k<Ee;k++) acc = fmaf(row[k], W[k*Ee + e], acc);
  mh[(size_t)r*Ee + e] = acc + bias[e] + encl[(size_t)r*Ee + e] + loadv[r]*capw[e];
}

// ---------------------------------------------------------------- score via batched GEMM
__global__ __launch_bounds__(256) void xt_k(
    const float* __restrict__ x, float* __restrict__ xT)
{
  __shared__ float T[32][33];
  int n0 = blockIdx.x * 32;
  int k0 = blockIdx.y * 32;
  int b  = blockIdx.z;
  int t  = threadIdx.x;
  int row = t >> 3;
  int c4  = (t & 7) << 2;

  int n = n0 + row;
  float4 v = make_float4(0.f,0.f,0.f,0.f);
  if (n < NT) v = *(const float4*)(x + ((size_t)(b*NT + n))*Ee + k0 + c4);
  T[c4+0][row] = v.x; T[c4+1][row] = v.y; T[c4+2][row] = v.z; T[c4+3][row] = v.w;
  __syncthreads();

  const float SC = 0.08838834764831845f;
  float4 o;
  o.x = T[row][c4+0]*SC; o.y = T[row][c4+1]*SC;
  o.z = T[row][c4+2]*SC; o.w = T[row][c4+3]*SC;
  *(float4*)(xT + ((size_t)(b*Ee + k0 + row))*SNP + n0 + c4) = o;
}

__global__ __launch_bounds__(256) void score_gemm_k(
    const float* __restrict__ qref, const float* __restrict__ xT,
    float* __restrict__ score)
{
  __shared__ __align__(16) float As[2][16][68];
  __shared__ __align__(16) float Bs[2][16][68];
  int tid = threadIdx.x;
  int tx = tid & 15, ty = tid >> 4;
  int m0 = blockIdx.x * 64;
  int n0 = blockIdx.y * 64;
  int b  = blockIdx.z;

  const float* A = qref + (size_t)b*Pp*Ee;
  const float* W = xT   + (size_t)b*Ee*SNP;
  float*       C = score + (size_t)b*Pp*SNP;

  float acc[4][4];
  #pragma unroll
  for (int i=0;i<4;i++)
    #pragma unroll
    for (int j=0;j<4;j++) acc[i][j] = 0.f;

  int ar = tid >> 2;
  int ak = (tid & 3) << 2;
  int br = tid >> 4;
  int bc = (tid & 15) << 2;

  const float* Ap = A + (size_t)(m0 + ar)*Ee + ak;
  const float* Wp = W + (size_t)br*SNP + n0 + bc;
  bool aok = (m0 + ar) < Pp;

  float4 av = aok ? *(const float4*)(Ap) : make_float4(0.f,0.f,0.f,0.f);
  float4 wv = *(const float4*)(Wp);

  for (int t = 0; t < 8; ++t) {
    int cur = t & 1;
    As[cur][ak+0][ar] = av.x; As[cur][ak+1][ar] = av.y;
    As[cur][ak+2][ar] = av.z; As[cur][ak+3][ar] = av.w;
    *(float4*)(&Bs[cur][br][bc]) = wv;
    __syncthreads();
    if (t+1 < 8) {
      av = aok ? *(const float4*)(Ap + (t+1)*16) : make_float4(0.f,0.f,0.f,0.f);
      wv = *(const float4*)(Wp + (size_t)(t+1)*16*SNP);
    }
    #pragma unroll
    for (int k=0;k<16;k++){
      float4 a4 = *(const float4*)(&As[cur][k][ty*4]);
      float4 b4 = *(const float4*)(&Bs[cur][k][tx*4]);
      float avv[4] = {a4.x,a4.y,a4.z,a4.w};
      float bvv[4] = {b4.x,b4.y,b4.z,b4.w};
      #pragma unroll
      for (int i=0;i<4;i++)
        #pragma unroll
        for (int j=0;j<4;j++)
          acc[i][j] = fmaf(avv[i], bvv[j], acc[i][j]);
    }
    __syncthreads();
  }

  #pragma unroll
  for (int i=0;i<4;i++){
    int row = m0 + ty*4 + i;
    if (row >= Pp) continue;
    float4 o;
    o.x = acc[i][0]; o.y = acc[i][1]; o.z = acc[i][2]; o.w = acc[i][3];
    *(float4*)(C + (size_t)row*SNP + n0 + tx*4) = o;
  }
}

// ---------------------------------------------------------------- threefry noise
__device__ __forceinline__ unsigned rotl32(unsigned x, int r){ return (x<<r)|(x>>(32-r)); }

__device__ float tf_normal(unsigned idx)
{
  unsigned x0 = 0u;
  unsigned x1 = idx;
  const unsigned ks[3] = {0u, 42u, 0u ^ 42u ^ 0x1BD11BDAu};
  x0 += ks[0]; x1 += ks[1];
  const int rotA[4] = {13,15,26,6};
  const int rotB[4] = {17,29,16,24};
  #pragma unroll
  for (int i=0;i<5;i++){
    #pragma unroll
    for (int q=0;q<4;q++){
      int rr = (i&1) ? rotB[q] : rotA[q];
      x0 += x1; x1 = rotl32(x1, rr); x1 ^= x0;
    }
    x0 += ks[(i+1)%3];
    x1 += ks[(i+2)%3] + (unsigned)(i+1);
  }
  unsigned bits = x0 ^ x1;
  float f = __uint_as_float((bits >> 9) | 0x3f800000u) - 1.0f;
  const float lo = -0.99999994f;
  float u = f * 2.0f + lo;
  u = fmaxf(lo, u);
  float w = -log1pf(-u*u);
  float p;
  if (w < 5.0f) {
    w -= 2.5f;
    p = 2.81022636e-08f;
    p = fmaf(p, w, 3.43273939e-07f);
    p = fmaf(p, w, -3.5233877e-06f);
    p = fmaf(p, w, -4.39150654e-06f);
    p = fmaf(p, w, 0.00021858087f);
    p = fmaf(p, w, -0.00125372503f);
    p = fmaf(p, w, -0.00417768164f);
    p = fmaf(p, w, 0.246640727f);
    p = fmaf(p, w, 1.50140941f);
  } else {
    w = sqrtf(w) - 3.0f;
    p = -0.000200214257f;
    p = fmaf(p, w, 0.000100950558f);
    p = fmaf(p, w, 0.00134934322f);
    p = fmaf(p, w, -0.00367342844f);
    p = fmaf(p, w, 0.00573950773f);
    p = fmaf(p, w, -0.0076224613f);
    p = fmaf(p, w, 0.00943887047f);
    p = fmaf(p, w, 1.00167406f);
    p = fmaf(p, w, 2.83297682f);
  }
  return 1.4142135623730951f * (p * u);
}

// ---------------------------------------------------------------- finalize (f32)
__global__ __launch_bounds__(512) void final_k(
    const float* __restrict__ score, const float* __restrict__ cur_dist,
    const float* __restrict__ ninf, float* __restrict__ out)
{
  __shared__ float smn[8], smx[8], sm2[8], ss[8];
  const float NM = (float)(50.0/501.0);
  const float C1 = (float)(1.0 - 50.0/501.0);
  int r = blockIdx.x;
  int t = threadIdx.x;
  int wid = t >> 6, lane = t & 63;

  float cd = 0.f;
  float mn = 1e30f, mx = -1e30f;
  if (t < NT) { cd = cur_dist[(size_t)r*NT + t]; mn = cd; mx = cd; }
  #pragma unroll
  for (int off=32; off>=1; off>>=1){
    mn = fminf(mn, __shfl_xor(mn, off));
    mx = fmaxf(mx, __shfl_xor(mx, off));
  }
  if (lane == 0){ smn[wid] = mn; smx[wid] = mx; }
  __syncthreads();
  float dmin = smn[0], dmax = smx[0];
  #pragma unroll
  for (int i=1;i<8;i++){ dmin = fminf(dmin, smn[i]); dmax = fmaxf(dmax, smx[i]); }

  float sval = -1e30f;
  if (t < NT) {
    float nd = (cd - dmin) / (dmax - dmin + 1e-6f);
    float z  = tf_normal((unsigned)r*501u + (unsigned)t);
    float s  = score[(size_t)r*SNP + t] - C1*logf(nd + 1e-6f) + (z*0.2f + 0.5f)*NM;
    sval = 10.0f*tanhf(s) + ninf[(size_t)r*NT + t];
  }
  float mv = sval;
  #pragma unroll
  for (int off=32; off>=1; off>>=1) mv = fmaxf(mv, __shfl_xor(mv, off));
  if (lane == 0) sm2[wid] = mv;
  __syncthreads();
  float smax = sm2[0];
  #pragma unroll
  for (int i=1;i<8;i++) smax = fmaxf(smax, sm2[i]);

  float e = (t < NT) ? expf(sval - smax) : 0.f;
  float sv = e;
  #pragma unroll
  for (int off=32; off>=1; off>>=1) sv += __shfl_xor(sv, off);
  if (lane == 0) ss[wid] = sv;
  __syncthreads();
  float ssum = ss[0];
  #pragma unroll
  for (int i=1;i<8;i++) ssum += ss[i];

  if (t < NT) out[(size_t)r*NT + t] = e / ssum;
}

// ---------------------------------------------------------------- launch
extern "C" void kernel_launch(void* const* d_in, const int* in_sizes, int n_in,
                              void* d_out, int out_size, void* d_ws, size_t ws_size,
                              hipStream_t stream)
{
  (void)in_sizes; (void)n_in; (void)out_size; (void)ws_size;
  const float* depot_xy    = (const float*)d_in[0];
  const float* node_xy     = (const float*)d_in[1];
  const float* node_demand = (const float*)d_in[2];
  const float* loadv       = (const float*)d_in[3];
  const float* cur_dist    = (const float*)d_in[4];
  const float* ninf        = (const float*)d_in[5];
  const int*   cur_node    = (const int*)d_in[6];
  const float* emb_depot_w = (const float*)d_in[7];
  const float* emb_depot_b = (const float*)d_in[8];
  const float* emb_node_w  = (const float*)d_in[9];
  const float* emb_node_b  = (const float*)d_in[10];
  const float* enc_wq      = (const float*)d_in[11];
  const float* enc_wk      = (const float*)d_in[12];
  const float* enc_wv      = (const float*)d_in[13];
  const float* enc_comb_w  = (const float*)d_in[14];
  const float* enc_comb_b  = (const float*)d_in[15];
  const float* enc_ff1_w   = (const float*)d_in[16];
  const float* enc_ff1_b   = (const float*)d_in[17];
  const float* enc_ff2_w   = (const float*)d_in[18];
  const float* enc_ff2_b   = (const float*)d_in[19];
  const float* dec_wq_last = (const float*)d_in[20];
  const float* dec_wk      = (const float*)d_in[21];
  const float* dec_wv      = (const float*)d_in[22];
  const float* dec_comb_w  = (const float*)d_in[23];
  const float* dec_comb_b  = (const float*)d_in[24];
  const float* dec_cap_w   = (const float*)d_in[25];
  const float* dec_ff1_w   = (const float*)d_in[26];
  const float* dec_ff1_b   = (const float*)d_in[27];
  const float* dec_ff2_w   = (const float*)d_in[28];
  const float* dec_ff2_b   = (const float*)d_in[29];

  float* ws = (float*)d_ws;
  const size_t SZ = (size_t)Mtok*Ee;   // 1,026,048
  float* xb    = ws + 0*SZ;
  float* qkvb  = ws + 1*SZ;            // enc QKV [Mtok][384]; dec KV [Mtok][256]
  float* atb   = ws + 4*SZ;            // enc part_l; dec qref
  float* o1b   = ws + 5*SZ;            // comb out; dec part_l; score
  float* ffb   = ws + 6*SZ;            // FF scratch (4*SZ); part_o; xT
  float* encPk = ws + 10*SZ;
  float* decPk = encPk + ENCP;
  float* part_o  = ffb;
  float* epart_l = atb;
  float* dpart_o = ffb;
  float* dpart_l = o1b;
  float* encl  = qkvb + 2*SZ;
  float* qdec  = encl + 204800;
  float* mhb   = qdec + 204800;
  float* qrefb = atb;
  float* ffh2  = ffb;
  float* xTb   = ffb;
  float* scoreb= o1b;

  pack_k<<<(ENCP + DECP + 255)/256, 256, 0, stream>>>(
      enc_wq, enc_wk, enc_wv, dec_wk, dec_wv, encPk, decPk);

  embed_k<<<(Mtok*Ee + 255)/256, 256, 0, stream>>>(
      depot_xy, node_xy, node_demand, emb_depot_w, emb_depot_b,
      emb_node_w, emb_node_b, xb);

  dim3 gqkv((Mtok + 63)/64, 384/64);
  dim3 gcombg((Mtok + 63)/64, Ee/64);
  dim3 gff ((Mtok + 63)/64, Ff/64);
  dim3 g128((Mtok + 63)/64, Ee/64);
  for (int l = 0; l < Ll; ++l) {
    gemm_k<<<gqkv, 256, 0, stream>>>(xb, encPk + (size_t)l*128*384, nullptr, nullptr, qkvb, Mtok, 384, Ee, 0);
    attn_enc_k<<<Bb*Hh*SPLIT, 256, 0, stream>>>(qkvb, part_o, epart_l);
    comb_gemm_k<<<gcombg, 256, 0, stream>>>(part_o, epart_l, enc_comb_w + (size_t)l*Ee*Ee,
                                            enc_comb_b + l*Ee, xb, o1b);
    gemm_k<<<gff, 256, 0, stream>>>(o1b, enc_ff1_w + (size_t)l*Ee*Ff, enc_ff1_b + l*Ff, nullptr, ffb, Mtok, Ff, Ee, 1);
    gemm_k<<<g128, 256, 0, stream>>>(ffb, enc_ff2_w + (size_t)l*Ff*Ee, enc_ff2_b + l*Ee, o1b, xb, Mtok, Ee, Ff, 0);
  }

  // decoder
  dim3 gkv((Mtok + 63)/64, 256/64);
  gemm_k<<<gkv, 256, 0, stream>>>(xb, decPk, nullptr, nullptr, qkvb, Mtok, 256, Ee, 0);
  decq_k<<<PR, 128, 0, stream>>>(xb, cur_node, loadv, dec_wq_last, qdec, encl);
  attn_dec_k<<<Bb*Hh*DSPLIT, 128, 0, stream>>>(qdec, qkvb, ninf, dpart_o, dpart_l);
  dec_comb_k<<<PR, 128, 0, stream>>>(dpart_o, dpart_l, dec_comb_w, dec_comb_b, encl, loadv, dec_cap_w, mhb);
  dim3 gd1((PR + 63)/64, Ff/64);
  gemm_k<<<gd1, 256, 0, stream>>>(mhb, dec_ff1_w, dec_ff1_b, nullptr, ffh2, PR, Ff, Ee, 1);
  dim3 gd2((PR + 63)/64, Ee/64);
  gemm_k<<<gd2, 256, 0, stream>>>(ffh2, dec_ff2_w, dec_ff2_b, mhb, qrefb, PR, Ee, Ff, 0);
  dim3 gxt(16, 4, 16);
  xt_k<<<gxt, 256, 0, stream>>>(xb, xTb);
  dim3 gsc(2, 8, 16);
  score_gemm_k<<<gsc, 256, 0, stream>>>(qrefb, xTb, scoreb);
  final_k<<<PR, 512, 0, stream>>>(scoreb, cur_dist, ninf, (float*)d_out);
}

// Round 15
// 974.634 us; speedup vs baseline: 1.0060x; 1.0060x over previous
//
#include <hip/hip_runtime.h>
#include <math.h>

#define Bb 16
#define Nn 500
#define NT 501
#define Pp 100
#define Ee 128
#define Hh 8
#define Dd 16
#define Ff 512
#define Ll 6
#define Mtok (Bb*NT)   // 8016
#define PR (Bb*Pp)     // 1600
#define TJ 32          // attn_enc KV tile rows
#define SPLIT 4        // encoder KV-split (126,126,126,123)
#define KSEG 126
#define DSPLIT 16      // decoder KV-split
#define DSEG 32
#define ENCP (6*128*384)
#define DECP (128*256)
#define SNP 512        // padded score row stride
#define KP 36          // LDS bf16 row pitch (ushorts)

typedef __attribute__((ext_vector_type(8))) short bf16x8;
typedef __attribute__((ext_vector_type(4))) float f32x4;

__device__ __forceinline__ unsigned short bfhi(float x){
  union { float f; unsigned u; } c; c.f = x; return (unsigned short)(c.u >> 16);
}
__device__ __forceinline__ float bff(unsigned short h){
  union { float f; unsigned u; } c; c.u = ((unsigned)h) << 16; return c.f;
}
__device__ __forceinline__ uint2 pack4(unsigned short a, unsigned short b,
                                       unsigned short c, unsigned short d){
  uint2 r; r.x = (unsigned)a | ((unsigned)b << 16);
  r.y = (unsigned)c | ((unsigned)d << 16); return r;
}
__device__ __forceinline__ unsigned pkhl(float f){
  unsigned short h = bfhi(f);
  unsigned short l = bfhi(f - bff(h));
  return (unsigned)h | ((unsigned)l << 16);
}

// ---------------------------------------------------------------- weight packing
__global__ __launch_bounds__(256) void pack_k(
    const float* __restrict__ ewq, const float* __restrict__ ewk, const float* __restrict__ ewv,
    const float* __restrict__ dwk, const float* __restrict__ dwv,
    float* __restrict__ encP, float* __restrict__ decP)
{
  int i = blockIdx.x*256 + threadIdx.x;
  if (i < ENCP) {
    int l = i / (128*384); int rem = i - l*128*384; int k = rem / 384; int n = rem - k*384;
    float v;
    if (n < 128)      v = ewq[((size_t)l*128 + k)*128 + n];
    else if (n < 256) v = ewk[((size_t)l*128 + k)*128 + (n-128)];
    else              v = ewv[((size_t)l*128 + k)*128 + (n-256)];
    encP[i] = v;
  } else {
    int j = i - ENCP;
    if (j < DECP) {
      int k = j >> 8; int n = j & 255;
      decP[j] = (n < 128) ? dwk[k*128 + n] : dwv[k*128 + (n-128)];
    }
  }
}

// split+transpose weights: dst[n][k] = pack(hi,lo) of src[k][n]; z = layer
__global__ __launch_bounds__(256) void wt_pack_k(
    const float* __restrict__ src, unsigned* __restrict__ dst, int K, int N)
{
  src += (size_t)blockIdx.z * K * N;
  dst += (size_t)blockIdx.z * K * N;
  __shared__ float T[32][33];
  int n0 = blockIdx.x * 32, k0 = blockIdx.y * 32;
  int t = threadIdx.x;
  int row = t >> 3;            // 0..31
  int c4  = (t & 7) << 2;      // 0..28

  float4 v = *(const float4*)(src + (size_t)(k0 + row)*N + n0 + c4);
  T[c4+0][row] = v.x; T[c4+1][row] = v.y; T[c4+2][row] = v.z; T[c4+3][row] = v.w;
  __syncthreads();

  uint4 o;
  o.x = pkhl(T[row][c4+0]); o.y = pkhl(T[row][c4+1]);
  o.z = pkhl(T[row][c4+2]); o.w = pkhl(T[row][c4+3]);
  *(uint4*)(dst + (size_t)(n0 + row)*K + k0 + c4) = o;
}

// ---------------------------------------------------------------- embed
__global__ __launch_bounds__(256) void embed_k(
    const float* __restrict__ depot_xy, const float* __restrict__ node_xy,
    const float* __restrict__ node_demand,
    const float* __restrict__ wD, const float* __restrict__ bD,
    const float* __restrict__ wN, const float* __restrict__ bN,
    float* __restrict__ x)
{
  int t = blockIdx.x*256 + threadIdx.x;
  if (t >= Mtok*Ee) return;
  int e   = t & (Ee-1);
  int tok = t >> 7;
  int b   = tok / NT;
  int n   = tok - b*NT;
  float v;
  if (n == 0) {
    v = depot_xy[b*2+0]*wD[0*Ee+e] + depot_xy[b*2+1]*wD[1*Ee+e] + bD[e];
  } else {
    int nn = n - 1;
    float c0 = node_xy[(b*Nn + nn)*2 + 0];
    float c1 = node_xy[(b*Nn + nn)*2 + 1];
    float c2 = node_demand[b*Nn + nn];
    v = c0*wN[0*Ee+e] + c1*wN[1*Ee+e] + c2*wN[2*Ee+e] + bN[e];
  }
  x[(size_t)tok*Ee + e] = v;
}

// ---------------------------------------------------------------- GEMM (split-bf16 MFMA, pre-split W)
// C[M,N] = A[M,K] @ W[K,N]  via Wt[N][K] packed (bf16hi | bf16lo<<16).
// A*W ~= Ah*Wh + Ah*Wl + Al*Wh.  64x64 tile, BK=32, 4 waves.
__global__ __launch_bounds__(256) void gemm_k(
    const float* __restrict__ A, const unsigned* __restrict__ Wt,
    const float* __restrict__ bias, const float* __restrict__ res,
    float* __restrict__ C, int M, int N, int K, int relu)
{
  __shared__ __align__(16) unsigned short Ah[2][64][KP];
  __shared__ __align__(16) unsigned short Al[2][64][KP];
  __shared__ __align__(16) unsigned short Bh[2][64][KP];   // [n][k]
  __shared__ __align__(16) unsigned short Bl[2][64][KP];

  int tid = threadIdx.x;
  int m0 = blockIdx.x * 64, n0 = blockIdx.y * 64;
  int wvid = tid >> 6;
  int lane = tid & 63;
  int lrow = lane & 15;
  int lk8  = (lane >> 4) * 8;

  f32x4 acc0 = {0.f,0.f,0.f,0.f}, acc1 = acc0, acc2 = acc0, acc3 = acc0;

  int ar = tid >> 2;              // 0..63 A row
  int ac = (tid & 3) << 2;        // k 0,4,8,12
  const float* Ap = A + (size_t)(m0 + ar)*K + ac;
  bool aok = (m0 + ar) < M;

  int wr2 = tid >> 2;             // 0..63 n row
  int wcu = (tid & 3) << 3;       // k 0,8,16,24
  const unsigned* Wp = Wt + (size_t)(n0 + wr2)*K + wcu;

  float4 zz = make_float4(0.f,0.f,0.f,0.f);
  float4 av0 = aok ? *(const float4*)(Ap)      : zz;
  float4 av1 = aok ? *(const float4*)(Ap + 16) : zz;
  uint4 w0 = *(const uint4*)(Wp);
  uint4 w1 = *(const uint4*)(Wp + 4);

  int nk = K >> 5;
  for (int t = 0; t < nk; ++t) {
    int cur = t & 1;
    // ---- stage A (split hi/lo, [m][k]) ----
    {
      unsigned short h0=bfhi(av0.x), h1=bfhi(av0.y), h2=bfhi(av0.z), h3=bfhi(av0.w);
      unsigned short l0=bfhi(av0.x-bff(h0)), l1=bfhi(av0.y-bff(h1)),
                     l2=bfhi(av0.z-bff(h2)), l3=bfhi(av0.w-bff(h3));
      *(uint2*)&Ah[cur][ar][ac] = pack4(h0,h1,h2,h3);
      *(uint2*)&Al[cur][ar][ac] = pack4(l0,l1,l2,l3);
      h0=bfhi(av1.x); h1=bfhi(av1.y); h2=bfhi(av1.z); h3=bfhi(av1.w);
      l0=bfhi(av1.x-bff(h0)); l1=bfhi(av1.y-bff(h1));
      l2=bfhi(av1.z-bff(h2)); l3=bfhi(av1.w-bff(h3));
      *(uint2*)&Ah[cur][ar][ac+16] = pack4(h0,h1,h2,h3);
      *(uint2*)&Al[cur][ar][ac+16] = pack4(l0,l1,l2,l3);
    }
    // ---- stage W (pre-split: perm-unpack, vector writes, [n][k]) ----
    {
      unsigned bh0=__builtin_amdgcn_perm(w0.y,w0.x,0x05040100u);
      unsigned bh1=__builtin_amdgcn_perm(w0.w,w0.z,0x05040100u);
      unsigned bh2=__builtin_amdgcn_perm(w1.y,w1.x,0x05040100u);
      unsigned bh3=__builtin_amdgcn_perm(w1.w,w1.z,0x05040100u);
      unsigned bl0=__builtin_amdgcn_perm(w0.y,w0.x,0x07060302u);
      unsigned bl1=__builtin_amdgcn_perm(w0.w,w0.z,0x07060302u);
      unsigned bl2=__builtin_amdgcn_perm(w1.y,w1.x,0x07060302u);
      unsigned bl3=__builtin_amdgcn_perm(w1.w,w1.z,0x07060302u);
      *(uint2*)&Bh[cur][wr2][wcu]   = make_uint2(bh0,bh1);
      *(uint2*)&Bh[cur][wr2][wcu+4] = make_uint2(bh2,bh3);
      *(uint2*)&Bl[cur][wr2][wcu]   = make_uint2(bl0,bl1);
      *(uint2*)&Bl[cur][wr2][wcu+4] = make_uint2(bl2,bl3);
    }
    __syncthreads();
    if (t+1 < nk) {
      av0 = aok ? *(const float4*)(Ap + (size_t)(t+1)*32)      : zz;
      av1 = aok ? *(const float4*)(Ap + (size_t)(t+1)*32 + 16) : zz;
      w0 = *(const uint4*)(Wp + (size_t)(t+1)*32);
      w1 = *(const uint4*)(Wp + (size_t)(t+1)*32 + 4);
    }
    // ---- compute ----
    union FR { bf16x8 v; uint2 u[2]; };
    FR ah, al;
    ah.u[0] = *(const uint2*)&Ah[cur][wvid*16 + lrow][lk8];
    ah.u[1] = *(const uint2*)&Ah[cur][wvid*16 + lrow][lk8+4];
    al.u[0] = *(const uint2*)&Al[cur][wvid*16 + lrow][lk8];
    al.u[1] = *(const uint2*)&Al[cur][wvid*16 + lrow][lk8+4];
    #define DOFRAG(f, accv) { \
      FR bh, bl; \
      bh.u[0] = *(const uint2*)&Bh[cur][(f)*16 + lrow][lk8]; \
      bh.u[1] = *(const uint2*)&Bh[cur][(f)*16 + lrow][lk8+4]; \
      bl.u[0] = *(const uint2*)&Bl[cur][(f)*16 + lrow][lk8]; \
      bl.u[1] = *(const uint2*)&Bl[cur][(f)*16 + lrow][lk8+4]; \
      accv = __builtin_amdgcn_mfma_f32_16x16x32_bf16(ah.v, bh.v, accv, 0,0,0); \
      accv = __builtin_amdgcn_mfma_f32_16x16x32_bf16(ah.v, bl.v, accv, 0,0,0); \
      accv = __builtin_amdgcn_mfma_f32_16x16x32_bf16(al.v, bh.v, accv, 0,0,0); \
    }
    DOFRAG(0, acc0); DOFRAG(1, acc1); DOFRAG(2, acc2); DOFRAG(3, acc3);
    #undef DOFRAG
  }

  int crow0 = m0 + wvid*16 + (lane >> 4)*4;
  int col0  = n0 + lrow;
  #define WRFRAG(f, accv) { \
    int col = col0 + (f)*16; \
    float bvs = bias ? bias[col] : 0.f; \
    _Pragma("unroll") \
    for (int j=0;j<4;j++){ \
      int row = crow0 + j; \
      if (row < M) { \
        float v = accv[j] + bvs; \
        if (relu) v = fmaxf(v, 0.f); \
        if (res) v += res[(size_t)row*N + col]; \
        C[(size_t)row*N + col] = v; \
      } \
    } \
  }
  WRFRAG(0, acc0); WRFRAG(1, acc1); WRFRAG(2, acc2); WRFRAG(3, acc3);
  #undef WRFRAG
}

// ---------------------------------------------------------------- attention
__device__ __forceinline__ float dot4(float4 a, float4 b){
  return fmaf(a.x,b.x, fmaf(a.y,b.y, fmaf(a.z,b.z, a.w*b.w)));
}

// encoder self-attention v5: 256 threads, 2 queries/thread, KV-split, no max.
__global__ __launch_bounds__(256, 1) void attn_enc_k(
    const float* __restrict__ QKV, float* __restrict__ part_o,
    float* __restrict__ part_l)
{
  int blk = blockIdx.x;
  int s  = blk % SPLIT;
  int bh = blk / SPLIT;
  int h  = bh & (Hh-1);
  int b  = bh >> 3;
  int tid = threadIdx.x;
  int p0 = tid;
  int p1 = tid + 256;
  const int klo = s*KSEG;
  int kseg = NT - klo; if (kseg > KSEG) kseg = KSEG;

  __shared__ __align__(16) float4 Ks[2][TJ][4];
  __shared__ __align__(16) float4 Vs[2][TJ][4];

  int row = (tid >> 2) & 31;
  int lc  = tid & 3;
  bool isV = tid >= 128;
  const int kvoff = isV ? 256 : 128;

  bool vbq = p1 < NT;

  const float4* qp0 = (const float4*)(QKV + ((size_t)(b*NT + p0))*384 + h*Dd);
  float4 qa0=qp0[0], qa1=qp0[1], qa2=qp0[2], qa3=qp0[3];
  float4 qb0,qb1,qb2,qb3;
  if (vbq) {
    const float4* qp1 = (const float4*)(QKV + ((size_t)(b*NT + p1))*384 + h*Dd);
    qb0=qp1[0]; qb1=qp1[1]; qb2=qp1[2]; qb3=qp1[3];
  } else {
    qb0=qb1=qb2=qb3=make_float4(0,0,0,0);
  }

  if (row < kseg) {
    float4 v = *((const float4*)(QKV + ((size_t)(b*NT + klo + row))*384 + kvoff + h*Dd) + lc);
    if (isV) Vs[0][row][lc] = v; else Ks[0][row][lc] = v;
  }
  __syncthreads();

  float lA = 0.f, lB = 0.f;
  float4 oA0=make_float4(0,0,0,0), oA1=oA0, oA2=oA0, oA3=oA0;
  float4 oB0=oA0, oB1=oA0, oB2=oA0, oB3=oA0;
  const int ntiles = (kseg + TJ - 1)/TJ;
  int buf = 0;

  for (int t = 0; t < ntiles; ++t) {
    int j0 = t*TJ;
    if (t+1 < ntiles) {
      int jj = j0 + TJ + row;
      if (jj < kseg) {
        float4 v = *((const float4*)(QKV + ((size_t)(b*NT + klo + jj))*384 + kvoff + h*Dd) + lc);
        if (isV) Vs[buf^1][row][lc] = v; else Ks[buf^1][row][lc] = v;
      }
    }
    int jend = kseg - j0; if (jend > TJ) jend = TJ;

    #pragma unroll 2
    for (int jj = 0; jj < jend; ++jj) {
      float4 k0=Ks[buf][jj][0], k1=Ks[buf][jj][1], k2=Ks[buf][jj][2], k3=Ks[buf][jj][3];
      float sA = (dot4(qa0,k0)+dot4(qa1,k1)) + (dot4(qa2,k2)+dot4(qa3,k3));
      float sB = (dot4(qb0,k0)+dot4(qb1,k1)) + (dot4(qb2,k2)+dot4(qb3,k3));
      float wA = __expf(sA*0.25f);
      float wB = __expf(sB*0.25f);
      lA += wA; lB += wB;
      float4 v0=Vs[buf][jj][0], v1=Vs[buf][jj][1], v2=Vs[buf][jj][2], v3=Vs[buf][jj][3];
      oA0.x=fmaf(wA,v0.x,oA0.x); oA0.y=fmaf(wA,v0.y,oA0.y); oA0.z=fmaf(wA,v0.z,oA0.z); oA0.w=fmaf(wA,v0.w,oA0.w);
      oA1.x=fmaf(wA,v1.x,oA1.x); oA1.y=fmaf(wA,v1.y,oA1.y); oA1.z=fmaf(wA,v1.z,oA1.z); oA1.w=fmaf(wA,v1.w,oA1.w);
      oA2.x=fmaf(wA,v2.x,oA2.x); oA2.y=fmaf(wA,v2.y,oA2.y); oA2.z=fmaf(wA,v2.z,oA2.z); oA2.w=fmaf(wA,v2.w,oA2.w);
      oA3.x=fmaf(wA,v3.x,oA3.x); oA3.y=fmaf(wA,v3.y,oA3.y); oA3.z=fmaf(wA,v3.z,oA3.z); oA3.w=fmaf(wA,v3.w,oA3.w);
      oB0.x=fmaf(wB,v0.x,oB0.x); oB0.y=fmaf(wB,v0.y,oB0.y); oB0.z=fmaf(wB,v0.z,oB0.z); oB0.w=fmaf(wB,v0.w,oB0.w);
      oB1.x=fmaf(wB,v1.x,oB1.x); oB1.y=fmaf(wB,v1.y,oB1.y); oB1.z=fmaf(wB,v1.z,oB1.z); oB1.w=fmaf(wB,v1.w,oB1.w);
      oB2.x=fmaf(wB,v2.x,oB2.x); oB2.y=fmaf(wB,v2.y,oB2.y); oB2.z=fmaf(wB,v2.z,oB2.z); oB2.w=fmaf(wB,v2.w,oB2.w);
      oB3.x=fmaf(wB,v3.x,oB3.x); oB3.y=fmaf(wB,v3.y,oB3.y); oB3.z=fmaf(wB,v3.z,oB3.z); oB3.w=fmaf(wB,v3.w,oB3.w);
    }
    __syncthreads();
    buf ^= 1;
  }

  size_t r0 = ((size_t)s*128 + bh)*NT + p0;
  float4* po0 = (float4*)(part_o + r0*16);
  po0[0]=oA0; po0[1]=oA1; po0[2]=oA2; po0[3]=oA3;
  part_l[r0] = lA;
  if (vbq) {
    size_t r1 = ((size_t)s*128 + bh)*NT + p1;
    float4* po1 = (float4*)(part_o + r1*16);
    po1[0]=oB0; po1[1]=oB1; po1[2]=oB2; po1[3]=oB3;
    part_l[r1] = lB;
  }
}

// comb GEMM: C[Mtok][128] = combine(part)[Mtok][128] @ W + bias + res(xb).
__global__ __launch_bounds__(256) void comb_gemm_k(
    const float* __restrict__ part_o, const float* __restrict__ part_l,
    const float* __restrict__ W, const float* __restrict__ bias,
    const float* __restrict__ res, float* __restrict__ C)
{
  __shared__ __align__(16) float As[2][16][68];
  __shared__ __align__(16) float Bs[2][16][68];
  int tid = threadIdx.x;
  int tx = tid & 15, ty = tid >> 4;
  int m0 = blockIdx.x * 64, n0 = blockIdx.y * 64;
  float acc[4][4];
  #pragma unroll
  for (int i=0;i<4;i++)
    #pragma unroll
    for (int j=0;j<4;j++) acc[i][j] = 0.f;

  int ar = tid >> 2;
  int ak = (tid & 3) << 2;
  int br = tid >> 4;
  int bc = (tid & 15) << 2;

  int row = m0 + ar;
  bool aok = row < Mtok;
  int tok = aok ? row : 0;
  int bb = tok / NT;
  int p  = tok - bb*NT;
  const size_t pbase = ((size_t)(bb*8))*NT + p;

  const float* Wp = W + (size_t)br*Ee + n0 + bc;

  #define LOADA(t, dst) { \
    float4 o4 = make_float4(0.f,0.f,0.f,0.f); float l = 0.f; \
    _Pragma("unroll") \
    for (int s=0;s<SPLIT;s++){ \
      size_t idx = (size_t)s*((size_t)128*NT) + pbase + (size_t)(t)*NT; \
      float4 v = *(const float4*)(part_o + idx*16 + ak); \
      o4.x+=v.x; o4.y+=v.y; o4.z+=v.z; o4.w+=v.w; \
      l += part_l[idx]; \
    } \
    float inv = aok ? 1.f/l : 0.f; \
    dst = make_float4(o4.x*inv, o4.y*inv, o4.z*inv, o4.w*inv); \
  }

  float4 av; LOADA(0, av);
  float4 wv = *(const float4*)(Wp);

  for (int t = 0; t < 8; ++t) {
    int cur = t & 1;
    As[cur][ak+0][ar] = av.x; As[cur][ak+1][ar] = av.y;
    As[cur][ak+2][ar] = av.z; As[cur][ak+3][ar] = av.w;
    *(float4*)(&Bs[cur][br][bc]) = wv;
    __syncthreads();
    if (t+1 < 8) {
      LOADA(t+1, av);
      wv = *(const float4*)(Wp + (size_t)(t+1)*16*Ee);
    }
    #pragma unroll
    for (int k=0;k<16;k++){
      float4 a4 = *(const float4*)(&As[cur][k][ty*4]);
      float4 b4 = *(const float4*)(&Bs[cur][k][tx*4]);
      float avv[4] = {a4.x,a4.y,a4.z,a4.w};
      float bvv[4] = {b4.x,b4.y,b4.z,b4.w};
      #pragma unroll
      for (int i=0;i<4;i++)
        #pragma unroll
        for (int j=0;j<4;j++)
          acc[i][j] = fmaf(avv[i], bvv[j], acc[i][j]);
    }
  }
  #undef LOADA

  float4 bv = *(const float4*)(bias + n0 + tx*4);
  #pragma unroll
  for (int i=0;i<4;i++){
    int orow = m0 + ty*4 + i;
    if (orow >= Mtok) continue;
    float4 o;
    float4 rv = *(const float4*)(res + (size_t)orow*Ee + n0 + tx*4);
    o.x = acc[i][0] + bv.x + rv.x; o.y = acc[i][1] + bv.y + rv.y;
    o.z = acc[i][2] + bv.z + rv.z; o.w = acc[i][3] + bv.w + rv.w;
    *(float4*)(C + (size_t)orow*Ee + n0 + tx*4) = o;
  }
}

// decoder cross-attention: LDS-staged broadcast, DSPLIT=16 segments of 32.
__global__ __launch_bounds__(128) void attn_dec_k(
    const float* __restrict__ Q, const float* __restrict__ KV,
    const float* __restrict__ mask,
    float* __restrict__ part_o, float* __restrict__ part_l)
{
  int blk = blockIdx.x;
  int s  = blk & (DSPLIT-1);
  int bh = blk >> 4;
  int h  = bh & (Hh-1);
  int b  = bh >> 3;
  int klo = s*DSEG;
  int kn  = NT - klo; if (kn > DSEG) kn = DSEG;

  __shared__ __align__(16) float4 Ks[DSEG][4];
  __shared__ __align__(16) float4 Vs[DSEG][4];

  int tid = threadIdx.x;
  for (int i = tid; i < kn*8; i += 128) {
    int row  = i >> 3;
    int q8   = i & 7;
    int quad = q8 & 3;
    int isv  = q8 >> 2;
    float4 v = *(const float4*)(KV + ((size_t)(b*NT + klo + row))*256 + isv*128 + h*Dd + quad*4);
    if (isv) Vs[row][quad] = v; else Ks[row][quad] = v;
  }
  __syncthreads();

  int p = tid;
  if (p >= Pp) return;
  int r = b*Pp + p;
  const float4* qp = (const float4*)(Q + (size_t)r*Ee + h*Dd);
  float4 qa=qp[0], qb=qp[1], qc=qp[2], qd=qp[3];
  const float* mrow = mask + (size_t)r*NT + klo;

  float l = 0.f;
  float4 o0=make_float4(0,0,0,0), o1=o0, o2=o0, o3=o0;
  for (int j=0;j<kn;++j){
    float sc = (dot4(qa,Ks[j][0])+dot4(qb,Ks[j][1])) + (dot4(qc,Ks[j][2])+dot4(qd,Ks[j][3]));
    float w = __expf(sc*0.25f + mrow[j]);
    l += w;
    float4 v0=Vs[j][0],v1=Vs[j][1],v2=Vs[j][2],v3=Vs[j][3];
    o0.x=fmaf(w,v0.x,o0.x); o0.y=fmaf(w,v0.y,o0.y); o0.z=fmaf(w,v0.z,o0.z); o0.w=fmaf(w,v0.w,o0.w);
    o1.x=fmaf(w,v1.x,o1.x); o1.y=fmaf(w,v1.y,o1.y); o1.z=fmaf(w,v1.z,o1.z); o1.w=fmaf(w,v1.w,o1.w);
    o2.x=fmaf(w,v2.x,o2.x); o2.y=fmaf(w,v2.y,o2.y); o2.z=fmaf(w,v2.z,o2.z); o2.w=fmaf(w,v2.w,o2.w);
    o3.x=fmaf(w,v3.x,o3.x); o3.y=fmaf(w,v3.y,o3.y); o3.z=fmaf(w,v3.z,o3.z); o3.w=fmaf(w,v3.w,o3.w);
  }

  size_t rb = ((size_t)s*PR + r)*Hh + h;
  float4* po = (float4*)(part_o + rb*16);
  po[0]=o0; po[1]=o1; po[2]=o2; po[3]=o3;
  part_l[rb] = l;
}

// ---------------------------------------------------------------- decoder small ops
__global__ __launch_bounds__(128) void decq_k(
    const float* __restrict__ x, const int* __restrict__ cur,
    const float* __restrict__ loadv, const float* __restrict__ Wq,
    float* __restrict__ q, float* __restrict__ encl)
{
  __shared__ float row[Ee];
  int r = blockIdx.x, e = threadIdx.x;
  int b = r / Pp;
  int node = cur[r];
  float xv = x[((size_t)(b*NT + node))*Ee + e];
  encl[(size_t)r*Ee + e] = xv;
  row[e] = xv;
  __syncthreads();
  float acc = 0.f;
  #pragma unroll 4
  for (int k=0;k<Ee;k++) acc = fmaf(row[k], Wq[k*128 + e], acc);
  acc = fmaf(loadv[r], Wq[Ee*128 + e], acc);
  q[(size_t)r*128 + e] = acc;
}

__global__ __launch_bounds__(128) void dec_comb_k(
    const float* __restrict__ dpart_o, const float* __restrict__ dpart_l,
    const float* __restrict__ W, const float* __restrict__ bias,
    const float* __restrict__ encl, const float* __restrict__ loadv,
    const float* __restrict__ capw, float* __restrict__ mh)
{
  __shared__ float row[Ee];
  int r = blockIdx.x, e = threadIdx.x;
  int h = e >> 4, d = e & 15;
  const size_t S = (size_t)PR*Hh;
  size_t rb = (size_t)r*Hh + h;
  float L = 0.f, o = 0.f;
  #pragma unroll
  for (int s=0;s<DSPLIT;s++){
    L += dpart_l[(size_t)s*S + rb];
    o += dpart_o[((size_t)s*S + rb)*16 + d];
  }
  row[e] = o / L;
  __syncthreads();
  float acc = 0.f;
  #pragma unroll 4
  for (int k=0;k<Ee;k++) acc = fmaf(row[k], W[k*Ee + e], acc);
  mh[(size_t)r*Ee + e] = acc + bias[e] + encl[(size_t)r*Ee + e] + loadv[r]*capw[e];
}

// ---------------------------------------------------------------- score via batched GEMM
__global__ __launch_bounds__(256) void xt_k(
    const float* __restrict__ x, float* __restrict__ xT)
{
  __shared__ float T[32][33];
  int n0 = blockIdx.x * 32;
  int k0 = blockIdx.y * 32;
  int b  = blockIdx.z;
  int t  = threadIdx.x;
  int row = t >> 3;
  int c4  = (t & 7) << 2;

  int n = n0 + row;
  float4 v = make_float4(0.f,0.f,0.f,0.f);
  if (n < NT) v = *(const float4*)(x + ((size_t)(b*NT + n))*Ee + k0 + c4);
  T[c4+0][row] = v.x; T[c4+1][row] = v.y; T[c4+2][row] = v.z; T[c4+3][row] = v.w;
  __syncthreads();

  const float SC = 0.08838834764831845f;
  float4 o;
  o.x = T[row][c4+0]*SC; o.y = T[row][c4+1]*SC;
  o.z = T[row][c4+2]*SC; o.w = T[row][c4+3]*SC;
  *(float4*)(xT + ((size_t)(b*Ee + k0 + row))*SNP + n0 + c4) = o;
}

__global__ __launch_bounds__(256) void score_gemm_k(
    const float* __restrict__ qref, const float* __restrict__ xT,
    float* __restrict__ score)
{
  __shared__ __align__(16) float As[2][16][68];
  __shared__ __align__(16) float Bs[2][16][68];
  int tid = threadIdx.x;
  int tx = tid & 15, ty = tid >> 4;
  int m0 = blockIdx.x * 64;
  int n0 = blockIdx.y * 64;
  int b  = blockIdx.z;

  const float* A = qref + (size_t)b*Pp*Ee;
  const float* W = xT   + (size_t)b*Ee*SNP;
  float*       C = score + (size_t)b*Pp*SNP;

  float acc[4][4];
  #pragma unroll
  for (int i=0;i<4;i++)
    #pragma unroll
    for (int j=0;j<4;j++) acc[i][j] = 0.f;

  int ar = tid >> 2;
  int ak = (tid & 3) << 2;
  int br = tid >> 4;
  int bc = (tid & 15) << 2;

  const float* Ap = A + (size_t)(m0 + ar)*Ee + ak;
  const float* Wp = W + (size_t)br*SNP + n0 + bc;
  bool aok = (m0 + ar) < Pp;

  float4 av = aok ? *(const float4*)(Ap) : make_float4(0.f,0.f,0.f,0.f);
  float4 wv = *(const float4*)(Wp);

  for (int t = 0; t < 8; ++t) {
    int cur = t & 1;
    As[cur][ak+0][ar] = av.x; As[cur][ak+1][ar] = av.y;
    As[cur][ak+2][ar] = av.z; As[cur][ak+3][ar] = av.w;
    *(float4*)(&Bs[cur][br][bc]) = wv;
    __syncthreads();
    if (t+1 < 8) {
      av = aok ? *(const float4*)(Ap + (t+1)*16) : make_float4(0.f,0.f,0.f,0.f);
      wv = *(const float4*)(Wp + (size_t)(t+1)*16*SNP);
    }
    #pragma unroll
    for (int k=0;k<16;k++){
      float4 a4 = *(const float4*)(&As[cur][k][ty*4]);
      float4 b4 = *(const float4*)(&Bs[cur][k][tx*4]);
      float avv[4] = {a4.x,a4.y,a4.z,a4.w};
      float bvv[4] = {b4.x,b4.y,b4.z,b4.w};
      #pragma unroll
      for (int i=0;i<4;i++)
        #pragma unroll
        for (int j=0;j<4;j++)
          acc[i][j] = fmaf(avv[i], bvv[j], acc[i][j]);
    }
    __syncthreads();
  }

  #pragma unroll
  for (int i=0;i<4;i++){
    int row = m0 + ty*4 + i;
    if (row >= Pp) continue;
    float4 o;
    o.x = acc[i][0]; o.y = acc[i][1]; o.z = acc[i][2]; o.w = acc[i][3];
    *(float4*)(C + (size_t)row*SNP + n0 + tx*4) = o;
  }
}

// ---------------------------------------------------------------- threefry noise
__device__ __forceinline__ unsigned rotl32(unsigned x, int r){ return (x<<r)|(x>>(32-r)); }

__device__ float tf_normal(unsigned idx)
{
  unsigned x0 = 0u;
  unsigned x1 = idx;
  const unsigned ks[3] = {0u, 42u, 0u ^ 42u ^ 0x1BD11BDAu};
  x0 += ks[0]; x1 += ks[1];
  const int rotA[4] = {13,15,26,6};
  const int rotB[4] = {17,29,16,24};
  #pragma unroll
  for (int i=0;i<5;i++){
    #pragma unroll
    for (int q=0;q<4;q++){
      int rr = (i&1) ? rotB[q] : rotA[q];
      x0 += x1; x1 = rotl32(x1, rr); x1 ^= x0;
    }
    x0 += ks[(i+1)%3];
    x1 += ks[(i+2)%3] + (unsigned)(i+1);
  }
  unsigned bits = x0 ^ x1;
  float f = __uint_as_float((bits >> 9) | 0x3f800000u) - 1.0f;
  const float lo = -0.99999994f;
  float u = f * 2.0f + lo;
  u = fmaxf(lo, u);
  float w = -log1pf(-u*u);
  float p;
  if (w < 5.0f) {
    w -= 2.5f;
    p = 2.81022636e-08f;
    p = fmaf(p, w, 3.43273939e-07f);
    p = fmaf(p, w, -3.5233877e-06f);
    p = fmaf(p, w, -4.39150654e-06f);
    p = fmaf(p, w, 0.00021858087f);
    p = fmaf(p, w, -0.00125372503f);
    p = fmaf(p, w, -0.00417768164f);
    p = fmaf(p, w, 0.246640727f);
    p = fmaf(p, w, 1.50140941f);
  } else {
    w = sqrtf(w) - 3.0f;
    p = -0.000200214257f;
    p = fmaf(p, w, 0.000100950558f);
    p = fmaf(p, w, 0.00134934322f);
    p = fmaf(p, w, -0.00367342844f);
    p = fmaf(p, w, 0.00573950773f);
    p = fmaf(p, w, -0.0076224613f);
    p = fmaf(p, w, 0.00943887047f);
    p = fmaf(p, w, 1.00167406f);
    p = fmaf(p, w, 2.83297682f);
  }
  return 1.4142135623730951f * (p * u);
}

// ---------------------------------------------------------------- finalize (f32)
__global__ __launch_bounds__(512) void final_k(
    const float* __restrict__ score, const float* __restrict__ cur_dist,
    const float* __restrict__ ninf, float* __restrict__ out)
{
  __shared__ float smn[8], smx[8], sm2[8], ss[8];
  const float NM = (float)(50.0/501.0);
  const float C1 = (float)(1.0 - 50.0/501.0);
  int r = blockIdx.x;
  int t = threadIdx.x;
  int wid = t >> 6, lane = t & 63;

  float cd = 0.f;
  float mn = 1e30f, mx = -1e30f;
  if (t < NT) { cd = cur_dist[(size_t)r*NT + t]; mn = cd; mx = cd; }
  #pragma unroll
  for (int off=32; off>=1; off>>=1){
    mn = fminf(mn, __shfl_xor(mn, off));
    mx = fmaxf(mx, __shfl_xor(mx, off));
  }
  if (lane == 0){ smn[wid] = mn; smx[wid] = mx; }
  __syncthreads();
  float dmin = smn[0], dmax = smx[0];
  #pragma unroll
  for (int i=1;i<8;i++){ dmin = fminf(dmin, smn[i]); dmax = fmaxf(dmax, smx[i]); }

  float sval = -1e30f;
  if (t < NT) {
    float nd = (cd - dmin) / (dmax - dmin + 1e-6f);
    float z  = tf_normal((unsigned)r*501u + (unsigned)t);
    float s  = score[(size_t)r*SNP + t] - C1*logf(nd + 1e-6f) + (z*0.2f + 0.5f)*NM;
    sval = 10.0f*tanhf(s) + ninf[(size_t)r*NT + t];
  }
  float mv = sval;
  #pragma unroll
  for (int off=32; off>=1; off>>=1) mv = fmaxf(mv, __shfl_xor(mv, off));
  if (lane == 0) sm2[wid] = mv;
  __syncthreads();
  float smax = sm2[0];
  #pragma unroll
  for (int i=1;i<8;i++) smax = fmaxf(smax, sm2[i]);

  float e = (t < NT) ? expf(sval - smax) : 0.f;
  float sv = e;
  #pragma unroll
  for (int off=32; off>=1; off>>=1) sv += __shfl_xor(sv, off);
  if (lane == 0) ss[wid] = sv;
  __syncthreads();
  float ssum = ss[0];
  #pragma unroll
  for (int i=1;i<8;i++) ssum += ss[i];

  if (t < NT) out[(size_t)r*NT + t] = e / ssum;
}

// ---------------------------------------------------------------- launch
extern "C" void kernel_launch(void* const* d_in, const int* in_sizes, int n_in,
                              void* d_out, int out_size, void* d_ws, size_t ws_size,
                              hipStream_t stream)
{
  (void)in_sizes; (void)n_in; (void)out_size; (void)ws_size;
  const float* depot_xy    = (const float*)d_in[0];
  const float* node_xy     = (const float*)d_in[1];
  const float* node_demand = (const float*)d_in[2];
  const float* loadv       = (const float*)d_in[3];
  const float* cur_dist    = (const float*)d_in[4];
  const float* ninf        = (const float*)d_in[5];
  const int*   cur_node    = (const int*)d_in[6];
  const float* emb_depot_w = (const float*)d_in[7];
  const float* emb_depot_b = (const float*)d_in[8];
  const float* emb_node_w  = (const float*)d_in[9];
  const float* emb_node_b  = (const float*)d_in[10];
  const float* enc_wq      = (const float*)d_in[11];
  const float* enc_wk      = (const float*)d_in[12];
  const float* enc_wv      = (const float*)d_in[13];
  const float* enc_comb_w  = (const float*)d_in[14];
  const float* enc_comb_b  = (const float*)d_in[15];
  const float* enc_ff1_w   = (const float*)d_in[16];
  const float* enc_ff1_b   = (const float*)d_in[17];
  const float* enc_ff2_w   = (const float*)d_in[18];
  const float* enc_ff2_b   = (const float*)d_in[19];
  const float* dec_wq_last = (const float*)d_in[20];
  const float* dec_wk      = (const float*)d_in[21];
  const float* dec_wv      = (const float*)d_in[22];
  const float* dec_comb_w  = (const float*)d_in[23];
  const float* dec_comb_b  = (const float*)d_in[24];
  const float* dec_cap_w   = (const float*)d_in[25];
  const float* dec_ff1_w   = (const float*)d_in[26];
  const float* dec_ff1_b   = (const float*)d_in[27];
  const float* dec_ff2_w   = (const float*)d_in[28];
  const float* dec_ff2_b   = (const float*)d_in[29];

  float* ws = (float*)d_ws;
  const size_t SZ = (size_t)Mtok*Ee;   // 1,026,048
  float* xb    = ws + 0*SZ;
  float* qkvb  = ws + 1*SZ;            // enc QKV [Mtok][384]; dec KV [Mtok][256]
  float* atb   = ws + 4*SZ;            // enc part_l; dec qref
  float* o1b   = ws + 5*SZ;            // comb out; dec part_l; score
  float* ffb   = ws + 6*SZ;            // FF scratch (4*SZ); part_o; xT
  float* encPk = ws + 10*SZ;
  float* decPk = encPk + ENCP;
  // packed (hi|lo) transposed weights: after decPk
  unsigned* qkvT = (unsigned*)(decPk + DECP);       // 6*384*128
  unsigned* ff1T = qkvT + (size_t)6*384*128;        // 6*512*128
  unsigned* ff2T = ff1T + (size_t)6*512*128;        // 6*128*512
  unsigned* dkvT = ff2T + (size_t)6*128*512;        // 256*128
  unsigned* d1T  = dkvT + 256*128;                  // 512*128
  unsigned* d2T  = d1T + 512*128;                   // 128*512
  float* part_o  = ffb;
  float* epart_l = atb;
  float* dpart_o = ffb;
  float* dpart_l = o1b;
  float* encl  = qkvb + 2*SZ;
  float* qdec  = encl + 204800;
  float* mhb   = qdec + 204800;
  float* qrefb = atb;
  float* ffh2  = ffb;
  float* xTb   = ffb;
  float* scoreb= o1b;

  pack_k<<<(ENCP + DECP + 255)/256, 256, 0, stream>>>(
      enc_wq, enc_wk, enc_wv, dec_wk, dec_wv, encPk, decPk);
  wt_pack_k<<<dim3(384/32, 128/32, 6), 256, 0, stream>>>(encPk, qkvT, 128, 384);
  wt_pack_k<<<dim3(512/32, 128/32, 6), 256, 0, stream>>>(enc_ff1_w, ff1T, 128, 512);
  wt_pack_k<<<dim3(128/32, 512/32, 6), 256, 0, stream>>>(enc_ff2_w, ff2T, 512, 128);
  wt_pack_k<<<dim3(256/32, 128/32, 1), 256, 0, stream>>>(decPk, dkvT, 128, 256);
  wt_pack_k<<<dim3(512/32, 128/32, 1), 256, 0, stream>>>(dec_ff1_w, d1T, 128, 512);
  wt_pack_k<<<dim3(128/32, 512/32, 1), 256, 0, stream>>>(dec_ff2_w, d2T, 512, 128);

  embed_k<<<(Mtok*Ee + 255)/256, 256, 0, stream>>>(
      depot_xy, node_xy, node_demand, emb_depot_w, emb_depot_b,
      emb_node_w, emb_node_b, xb);

  dim3 gqkv((Mtok + 63)/64, 384/64);
  dim3 gcombg((Mtok + 63)/64, Ee/64);
  dim3 gff ((Mtok + 63)/64, Ff/64);
  dim3 g128((Mtok + 63)/64, Ee/64);
  for (int l = 0; l < Ll; ++l) {
    gemm_k<<<gqkv, 256, 0, stream>>>(xb, qkvT + (size_t)l*384*128, nullptr, nullptr, qkvb, Mtok, 384, Ee, 0);
    attn_enc_k<<<Bb*Hh*SPLIT, 256, 0, stream>>>(qkvb, part_o, epart_l);
    comb_gemm_k<<<gcombg, 256, 0, stream>>>(part_o, epart_l, enc_comb_w + (size_t)l*Ee*Ee,
                                            enc_comb_b + l*Ee, xb, o1b);
    gemm_k<<<gff, 256, 0, stream>>>(o1b, ff1T + (size_t)l*512*128, enc_ff1_b + l*Ff, nullptr, ffb, Mtok, Ff, Ee, 1);
    gemm_k<<<g128, 256, 0, stream>>>(ffb, ff2T + (size_t)l*128*512, enc_ff2_b + l*Ee, o1b, xb, Mtok, Ee, Ff, 0);
  }

  // decoder
  dim3 gkv((Mtok + 63)/64, 256/64);
  gemm_k<<<gkv, 256, 0, stream>>>(xb, dkvT, nullptr, nullptr, qkvb, Mtok, 256, Ee, 0);
  decq_k<<<PR, 128, 0, stream>>>(xb, cur_node, loadv, dec_wq_last, qdec, encl);
  attn_dec_k<<<Bb*Hh*DSPLIT, 128, 0, stream>>>(qdec, qkvb, ninf, dpart_o, dpart_l);
  dec_comb_k<<<PR, 128, 0, stream>>>(dpart_o, dpart_l, dec_comb_w, dec_comb_b, encl, loadv, dec_cap_w, mhb);
  dim3 gd1((PR + 63)/64, Ff/64);
  gemm_k<<<gd1, 256, 0, stream>>>(mhb, d1T, dec_ff1_b, nullptr, ffh2, PR, Ff, Ee, 1);
  dim3 gd2((PR + 63)/64, Ee/64);
  gemm_k<<<gd2, 256, 0, stream>>>(ffh2, d2T, dec_ff2_b, mhb, qrefb, PR, Ee, Ff, 0);
  dim3 gxt(16, 4, 16);
  xt_k<<<gxt, 256, 0, stream>>>(xb, xTb);
  dim3 gsc(2, 8, 16);
  score_gemm_k<<<gsc, 256, 0, stream>>>(qrefb, xTb, scoreb);
  final_k<<<PR, 512, 0, stream>>>(scoreb, cur_dist, ninf, (float*)d_out);
}

// Round 16
// 885.568 us; speedup vs baseline: 1.1072x; 1.1006x over previous
//
#include <hip/hip_runtime.h>
#include <math.h>

#define Bb 16
#define Nn 500
#define NT 501
#define Pp 100
#define Ee 128
#define Hh 8
#define Dd 16
#define Ff 512
#define Ll 6
#define Mtok (Bb*NT)   // 8016
#define PR (Bb*Pp)     // 1600
#define TJ 32          // attn_enc KV tile rows
#define SPLIT 4        // encoder KV-split (126,126,126,123)
#define KSEG 126
#define DSPLIT 16      // decoder KV-split
#define DSEG 32
#define ENCP (6*128*384)
#define DECP (128*256)
#define SNP 512        // padded score row stride

// ---------------------------------------------------------------- weight packing
__global__ __launch_bounds__(256) void pack_k(
    const float* __restrict__ ewq, const float* __restrict__ ewk, const float* __restrict__ ewv,
    const float* __restrict__ dwk, const float* __restrict__ dwv,
    float* __restrict__ encP, float* __restrict__ decP)
{
  int i = blockIdx.x*256 + threadIdx.x;
  if (i < ENCP) {
    int l = i / (128*384); int rem = i - l*128*384; int k = rem / 384; int n = rem - k*384;
    float v;
    if (n < 128)      v = ewq[((size_t)l*128 + k)*128 + n];
    else if (n < 256) v = ewk[((size_t)l*128 + k)*128 + (n-128)];
    else              v = ewv[((size_t)l*128 + k)*128 + (n-256)];
    encP[i] = v;
  } else {
    int j = i - ENCP;
    if (j < DECP) {
      int k = j >> 8; int n = j & 255;
      decP[j] = (n < 128) ? dwk[k*128 + n] : dwv[k*128 + (n-128)];
    }
  }
}

// ---------------------------------------------------------------- embed
__global__ __launch_bounds__(256) void embed_k(
    const float* __restrict__ depot_xy, const float* __restrict__ node_xy,
    const float* __restrict__ node_demand,
    const float* __restrict__ wD, const float* __restrict__ bD,
    const float* __restrict__ wN, const float* __restrict__ bN,
    float* __restrict__ x)
{
  int t = blockIdx.x*256 + threadIdx.x;
  if (t >= Mtok*Ee) return;
  int e   = t & (Ee-1);
  int tok = t >> 7;
  int b   = tok / NT;
  int n   = tok - b*NT;
  float v;
  if (n == 0) {
    v = depot_xy[b*2+0]*wD[0*Ee+e] + depot_xy[b*2+1]*wD[1*Ee+e] + bD[e];
  } else {
    int nn = n - 1;
    float c0 = node_xy[(b*Nn + nn)*2 + 0];
    float c1 = node_xy[(b*Nn + nn)*2 + 1];
    float c2 = node_demand[b*Nn + nn];
    v = c0*wN[0*Ee+e] + c1*wN[1*Ee+e] + c2*wN[2*Ee+e] + bN[e];
  }
  x[(size_t)tok*Ee + e] = v;
}

// ---------------------------------------------------------------- GEMM (f32, proven)
// C[M,N] = A[M,K] @ W[K,N]  (+bias)(relu)(+res).  N%64==0, K%16==0.
// Double-buffered LDS, 1 barrier/K-step, rows padded to 68 floats.
__global__ __launch_bounds__(256) void gemm_k(
    const float* __restrict__ A, const float* __restrict__ W,
    const float* __restrict__ bias, const float* __restrict__ res,
    float* __restrict__ C, int M, int N, int K, int relu)
{
  __shared__ __align__(16) float As[2][16][68];
  __shared__ __align__(16) float Bs[2][16][68];
  int tid = threadIdx.x;
  int tx = tid & 15, ty = tid >> 4;
  int m0 = blockIdx.x * 64, n0 = blockIdx.y * 64;
  float acc[4][4];
  #pragma unroll
  for (int i=0;i<4;i++)
    #pragma unroll
    for (int j=0;j<4;j++) acc[i][j] = 0.f;

  int ar = tid >> 2;
  int ak = (tid & 3) << 2;
  int br = tid >> 4;
  int bc = (tid & 15) << 2;

  const float* Ap = A + (size_t)(m0 + ar)*K + ak;
  const float* Wp = W + (size_t)br*N + n0 + bc;
  bool aok = (m0 + ar) < M;

  float4 av = aok ? *(const float4*)(Ap) : make_float4(0.f,0.f,0.f,0.f);
  float4 wv = *(const float4*)(Wp);

  int nk = K >> 4;
  for (int t = 0; t < nk; ++t) {
    int cur = t & 1;
    As[cur][ak+0][ar] = av.x; As[cur][ak+1][ar] = av.y;
    As[cur][ak+2][ar] = av.z; As[cur][ak+3][ar] = av.w;
    *(float4*)(&Bs[cur][br][bc]) = wv;
    __syncthreads();
    if (t+1 < nk) {
      av = aok ? *(const float4*)(Ap + (t+1)*16) : make_float4(0.f,0.f,0.f,0.f);
      wv = *(const float4*)(Wp + (size_t)(t+1)*16*N);
    }
    #pragma unroll
    for (int k=0;k<16;k++){
      float4 a4 = *(const float4*)(&As[cur][k][ty*4]);
      float4 b4 = *(const float4*)(&Bs[cur][k][tx*4]);
      float avv[4] = {a4.x,a4.y,a4.z,a4.w};
      float bvv[4] = {b4.x,b4.y,b4.z,b4.w};
      #pragma unroll
      for (int i=0;i<4;i++)
        #pragma unroll
        for (int j=0;j<4;j++)
          acc[i][j] = fmaf(avv[i], bvv[j], acc[i][j]);
    }
  }

  float4 bv = make_float4(0.f,0.f,0.f,0.f);
  if (bias) bv = *(const float4*)(bias + n0 + tx*4);
  #pragma unroll
  for (int i=0;i<4;i++){
    int row = m0 + ty*4 + i;
    if (row >= M) continue;
    float4 o;
    o.x = acc[i][0] + bv.x; o.y = acc[i][1] + bv.y;
    o.z = acc[i][2] + bv.z; o.w = acc[i][3] + bv.w;
    if (relu){ o.x=fmaxf(o.x,0.f); o.y=fmaxf(o.y,0.f); o.z=fmaxf(o.z,0.f); o.w=fmaxf(o.w,0.f); }
    if (res){
      float4 rv = *(const float4*)(res + (size_t)row*N + n0 + tx*4);
      o.x += rv.x; o.y += rv.y; o.z += rv.z; o.w += rv.w;
    }
    *(float4*)(C + (size_t)row*N + n0 + tx*4) = o;
  }
}

// ---------------------------------------------------------------- attention
__device__ __forceinline__ float dot4(float4 a, float4 b){
  return fmaf(a.x,b.x, fmaf(a.y,b.y, fmaf(a.z,b.z, a.w*b.w)));
}

// encoder self-attention v5: 256 threads, 2 queries/thread, KV-split, no max.
__global__ __launch_bounds__(256, 1) void attn_enc_k(
    const float* __restrict__ QKV, float* __restrict__ part_o,
    float* __restrict__ part_l)
{
  int blk = blockIdx.x;
  int s  = blk % SPLIT;
  int bh = blk / SPLIT;
  int h  = bh & (Hh-1);
  int b  = bh >> 3;
  int tid = threadIdx.x;
  int p0 = tid;
  int p1 = tid + 256;
  const int klo = s*KSEG;
  int kseg = NT - klo; if (kseg > KSEG) kseg = KSEG;

  __shared__ __align__(16) float4 Ks[2][TJ][4];
  __shared__ __align__(16) float4 Vs[2][TJ][4];

  int row = (tid >> 2) & 31;
  int lc  = tid & 3;
  bool isV = tid >= 128;
  const int kvoff = isV ? 256 : 128;

  bool vbq = p1 < NT;

  const float4* qp0 = (const float4*)(QKV + ((size_t)(b*NT + p0))*384 + h*Dd);
  float4 qa0=qp0[0], qa1=qp0[1], qa2=qp0[2], qa3=qp0[3];
  float4 qb0,qb1,qb2,qb3;
  if (vbq) {
    const float4* qp1 = (const float4*)(QKV + ((size_t)(b*NT + p1))*384 + h*Dd);
    qb0=qp1[0]; qb1=qp1[1]; qb2=qp1[2]; qb3=qp1[3];
  } else {
    qb0=qb1=qb2=qb3=make_float4(0,0,0,0);
  }

  if (row < kseg) {
    float4 v = *((const float4*)(QKV + ((size_t)(b*NT + klo + row))*384 + kvoff + h*Dd) + lc);
    if (isV) Vs[0][row][lc] = v; else Ks[0][row][lc] = v;
  }
  __syncthreads();

  float lA = 0.f, lB = 0.f;
  float4 oA0=make_float4(0,0,0,0), oA1=oA0, oA2=oA0, oA3=oA0;
  float4 oB0=oA0, oB1=oA0, oB2=oA0, oB3=oA0;
  const int ntiles = (kseg + TJ - 1)/TJ;
  int buf = 0;

  for (int t = 0; t < ntiles; ++t) {
    int j0 = t*TJ;
    if (t+1 < ntiles) {
      int jj = j0 + TJ + row;
      if (jj < kseg) {
        float4 v = *((const float4*)(QKV + ((size_t)(b*NT + klo + jj))*384 + kvoff + h*Dd) + lc);
        if (isV) Vs[buf^1][row][lc] = v; else Ks[buf^1][row][lc] = v;
      }
    }
    int jend = kseg - j0; if (jend > TJ) jend = TJ;

    #pragma unroll 2
    for (int jj = 0; jj < jend; ++jj) {
      float4 k0=Ks[buf][jj][0], k1=Ks[buf][jj][1], k2=Ks[buf][jj][2], k3=Ks[buf][jj][3];
      float sA = (dot4(qa0,k0)+dot4(qa1,k1)) + (dot4(qa2,k2)+dot4(qa3,k3));
      float sB = (dot4(qb0,k0)+dot4(qb1,k1)) + (dot4(qb2,k2)+dot4(qb3,k3));
      float wA = __expf(sA*0.25f);
      float wB = __expf(sB*0.25f);
      lA += wA; lB += wB;
      float4 v0=Vs[buf][jj][0], v1=Vs[buf][jj][1], v2=Vs[buf][jj][2], v3=Vs[buf][jj][3];
      oA0.x=fmaf(wA,v0.x,oA0.x); oA0.y=fmaf(wA,v0.y,oA0.y); oA0.z=fmaf(wA,v0.z,oA0.z); oA0.w=fmaf(wA,v0.w,oA0.w);
      oA1.x=fmaf(wA,v1.x,oA1.x); oA1.y=fmaf(wA,v1.y,oA1.y); oA1.z=fmaf(wA,v1.z,oA1.z); oA1.w=fmaf(wA,v1.w,oA1.w);
      oA2.x=fmaf(wA,v2.x,oA2.x); oA2.y=fmaf(wA,v2.y,oA2.y); oA2.z=fmaf(wA,v2.z,oA2.z); oA2.w=fmaf(wA,v2.w,oA2.w);
      oA3.x=fmaf(wA,v3.x,oA3.x); oA3.y=fmaf(wA,v3.y,oA3.y); oA3.z=fmaf(wA,v3.z,oA3.z); oA3.w=fmaf(wA,v3.w,oA3.w);
      oB0.x=fmaf(wB,v0.x,oB0.x); oB0.y=fmaf(wB,v0.y,oB0.y); oB0.z=fmaf(wB,v0.z,oB0.z); oB0.w=fmaf(wB,v0.w,oB0.w);
      oB1.x=fmaf(wB,v1.x,oB1.x); oB1.y=fmaf(wB,v1.y,oB1.y); oB1.z=fmaf(wB,v1.z,oB1.z); oB1.w=fmaf(wB,v1.w,oB1.w);
      oB2.x=fmaf(wB,v2.x,oB2.x); oB2.y=fmaf(wB,v2.y,oB2.y); oB2.z=fmaf(wB,v2.z,oB2.z); oB2.w=fmaf(wB,v2.w,oB2.w);
      oB3.x=fmaf(wB,v3.x,oB3.x); oB3.y=fmaf(wB,v3.y,oB3.y); oB3.z=fmaf(wB,v3.z,oB3.z); oB3.w=fmaf(wB,v3.w,oB3.w);
    }
    __syncthreads();
    buf ^= 1;
  }

  size_t r0 = ((size_t)s*128 + bh)*NT + p0;
  float4* po0 = (float4*)(part_o + r0*16);
  po0[0]=oA0; po0[1]=oA1; po0[2]=oA2; po0[3]=oA3;
  part_l[r0] = lA;
  if (vbq) {
    size_t r1 = ((size_t)s*128 + bh)*NT + p1;
    float4* po1 = (float4*)(part_o + r1*16);
    po1[0]=oB0; po1[1]=oB1; po1[2]=oB2; po1[3]=oB3;
    part_l[r1] = lB;
  }
}

// combine SPLIT partials (plain sums) -> O[b,q,h,d]
__global__ __launch_bounds__(256) void attn_comb_k(
    const float* __restrict__ part_o, const float* __restrict__ part_l,
    float* __restrict__ O)
{
  int t = blockIdx.x*256 + threadIdx.x;
  if (t >= 128*NT*16) return;
  int d  = t & 15;
  int rq = t >> 4;
  int q  = rq % NT;
  int bh = rq / NT;
  int h = bh & 7, b = bh >> 3;
  const size_t R = (size_t)128*NT;
  float L = 0.f, o = 0.f;
  #pragma unroll
  for (int s=0;s<SPLIT;s++){
    L += part_l[(size_t)s*R + rq];
    o += part_o[((size_t)s*R + rq)*16 + d];
  }
  O[((size_t)(b*NT + q))*Ee + h*Dd + d] = o / L;
}

// decoder cross-attention: LDS-staged broadcast, DSPLIT=16 segments of 32.
__global__ __launch_bounds__(128) void attn_dec_k(
    const float* __restrict__ Q, const float* __restrict__ KV,
    const float* __restrict__ mask,
    float* __restrict__ part_o, float* __restrict__ part_l)
{
  int blk = blockIdx.x;
  int s  = blk & (DSPLIT-1);
  int bh = blk >> 4;
  int h  = bh & (Hh-1);
  int b  = bh >> 3;
  int klo = s*DSEG;
  int kn  = NT - klo; if (kn > DSEG) kn = DSEG;

  __shared__ __align__(16) float4 Ks[DSEG][4];
  __shared__ __align__(16) float4 Vs[DSEG][4];

  int tid = threadIdx.x;
  for (int i = tid; i < kn*8; i += 128) {
    int row  = i >> 3;
    int q8   = i & 7;
    int quad = q8 & 3;
    int isv  = q8 >> 2;
    float4 v = *(const float4*)(KV + ((size_t)(b*NT + klo + row))*256 + isv*128 + h*Dd + quad*4);
    if (isv) Vs[row][quad] = v; else Ks[row][quad] = v;
  }
  __syncthreads();

  int p = tid;
  if (p >= Pp) return;
  int r = b*Pp + p;
  const float4* qp = (const float4*)(Q + (size_t)r*Ee + h*Dd);
  float4 qa=qp[0], qb=qp[1], qc=qp[2], qd=qp[3];
  const float* mrow = mask + (size_t)r*NT + klo;

  float l = 0.f;
  float4 o0=make_float4(0,0,0,0), o1=o0, o2=o0, o3=o0;
  for (int j=0;j<kn;++j){
    float sc = (dot4(qa,Ks[j][0])+dot4(qb,Ks[j][1])) + (dot4(qc,Ks[j][2])+dot4(qd,Ks[j][3]));
    float w = __expf(sc*0.25f + mrow[j]);
    l += w;
    float4 v0=Vs[j][0],v1=Vs[j][1],v2=Vs[j][2],v3=Vs[j][3];
    o0.x=fmaf(w,v0.x,o0.x); o0.y=fmaf(w,v0.y,o0.y); o0.z=fmaf(w,v0.z,o0.z); o0.w=fmaf(w,v0.w,o0.w);
    o1.x=fmaf(w,v1.x,o1.x); o1.y=fmaf(w,v1.y,o1.y); o1.z=fmaf(w,v1.z,o1.z); o1.w=fmaf(w,v1.w,o1.w);
    o2.x=fmaf(w,v2.x,o2.x); o2.y=fmaf(w,v2.y,o2.y); o2.z=fmaf(w,v2.z,o2.z); o2.w=fmaf(w,v2.w,o2.w);
    o3.x=fmaf(w,v3.x,o3.x); o3.y=fmaf(w,v3.y,o3.y); o3.z=fmaf(w,v3.z,o3.z); o3.w=fmaf(w,v3.w,o3.w);
  }

  size_t rb = ((size_t)s*PR + r)*Hh + h;
  float4* po = (float4*)(part_o + rb*16);
  po[0]=o0; po[1]=o1; po[2]=o2; po[3]=o3;
  part_l[rb] = l;
}

// ---------------------------------------------------------------- decoder small ops
__global__ __launch_bounds__(128) void decq_k(
    const float* __restrict__ x, const int* __restrict__ cur,
    const float* __restrict__ loadv, const float* __restrict__ Wq,
    float* __restrict__ q, float* __restrict__ encl)
{
  __shared__ float row[Ee];
  int r = blockIdx.x, e = threadIdx.x;
  int b = r / Pp;
  int node = cur[r];
  float xv = x[((size_t)(b*NT + node))*Ee + e];
  encl[(size_t)r*Ee + e] = xv;
  row[e] = xv;
  __syncthreads();
  float acc = 0.f;
  #pragma unroll 4
  for (int k=0;k<Ee;k++) acc = fmaf(row[k], Wq[k*128 + e], acc);
  acc = fmaf(loadv[r], Wq[Ee*128 + e], acc);
  q[(size_t)r*128 + e] = acc;
}

__global__ __launch_bounds__(128) void dec_comb_k(
    const float* __restrict__ dpart_o, const float* __restrict__ dpart_l,
    const float* __restrict__ W, const float* __restrict__ bias,
    const float* __restrict__ encl, const float* __restrict__ loadv,
    const float* __restrict__ capw, float* __restrict__ mh)
{
  __shared__ float row[Ee];
  int r = blockIdx.x, e = threadIdx.x;
  int h = e >> 4, d = e & 15;
  const size_t S = (size_t)PR*Hh;
  size_t rb = (size_t)r*Hh + h;
  float L = 0.f, o = 0.f;
  #pragma unroll
  for (int s=0;s<DSPLIT;s++){
    L += dpart_l[(size_t)s*S + rb];
    o += dpart_o[((size_t)s*S + rb)*16 + d];
  }
  row[e] = o / L;
  __syncthreads();
  float acc = 0.f;
  #pragma unroll 4
  for (int k=0;k<Ee;k++) acc = fmaf(row[k], W[k*Ee + e], acc);
  mh[(size_t)r*Ee + e] = acc + bias[e] + encl[(size_t)r*Ee + e] + loadv[r]*capw[e];
}

// ---------------------------------------------------------------- score via batched GEMM
__global__ __launch_bounds__(256) void xt_k(
    const float* __restrict__ x, float* __restrict__ xT)
{
  __shared__ float T[32][33];
  int n0 = blockIdx.x * 32;
  int k0 = blockIdx.y * 32;
  int b  = blockIdx.z;
  int t  = threadIdx.x;
  int row = t >> 3;
  int c4  = (t & 7) << 2;

  int n = n0 + row;
  float4 v = make_float4(0.f,0.f,0.f,0.f);
  if (n < NT) v = *(const float4*)(x + ((size_t)(b*NT + n))*Ee + k0 + c4);
  T[c4+0][row] = v.x; T[c4+1][row] = v.y; T[c4+2][row] = v.z; T[c4+3][row] = v.w;
  __syncthreads();

  const float SC = 0.08838834764831845f;
  float4 o;
  o.x = T[row][c4+0]*SC; o.y = T[row][c4+1]*SC;
  o.z = T[row][c4+2]*SC; o.w = T[row][c4+3]*SC;
  *(float4*)(xT + ((size_t)(b*Ee + k0 + row))*SNP + n0 + c4) = o;
}

__global__ __launch_bounds__(256) void score_gemm_k(
    const float* __restrict__ qref, const float* __restrict__ xT,
    float* __restrict__ score)
{
  __shared__ __align__(16) float As[2][16][68];
  __shared__ __align__(16) float Bs[2][16][68];
  int tid = threadIdx.x;
  int tx = tid & 15, ty = tid >> 4;
  int m0 = blockIdx.x * 64;
  int n0 = blockIdx.y * 64;
  int b  = blockIdx.z;

  const float* A = qref + (size_t)b*Pp*Ee;
  const float* W = xT   + (size_t)b*Ee*SNP;
  float*       C = score + (size_t)b*Pp*SNP;

  float acc[4][4];
  #pragma unroll
  for (int i=0;i<4;i++)
    #pragma unroll
    for (int j=0;j<4;j++) acc[i][j] = 0.f;

  int ar = tid >> 2;
  int ak = (tid & 3) << 2;
  int br = tid >> 4;
  int bc = (tid & 15) << 2;

  const float* Ap = A + (size_t)(m0 + ar)*Ee + ak;
  const float* Wp = W + (size_t)br*SNP + n0 + bc;
  bool aok = (m0 + ar) < Pp;

  float4 av = aok ? *(const float4*)(Ap) : make_float4(0.f,0.f,0.f,0.f);
  float4 wv = *(const float4*)(Wp);

  for (int t = 0; t < 8; ++t) {
    int cur = t & 1;
    As[cur][ak+0][ar] = av.x; As[cur][ak+1][ar] = av.y;
    As[cur][ak+2][ar] = av.z; As[cur][ak+3][ar] = av.w;
    *(float4*)(&Bs[cur][br][bc]) = wv;
    __syncthreads();
    if (t+1 < 8) {
      av = aok ? *(const float4*)(Ap + (t+1)*16) : make_float4(0.f,0.f,0.f,0.f);
      wv = *(const float4*)(Wp + (size_t)(t+1)*16*SNP);
    }
    #pragma unroll
    for (int k=0;k<16;k++){
      float4 a4 = *(const float4*)(&As[cur][k][ty*4]);
      float4 b4 = *(const float4*)(&Bs[cur][k][tx*4]);
      float avv[4] = {a4.x,a4.y,a4.z,a4.w};
      float bvv[4] = {b4.x,b4.y,b4.z,b4.w};
      #pragma unroll
      for (int i=0;i<4;i++)
        #pragma unroll
        for (int j=0;j<4;j++)
          acc[i][j] = fmaf(avv[i], bvv[j], acc[i][j]);
    }
    __syncthreads();
  }

  #pragma unroll
  for (int i=0;i<4;i++){
    int row = m0 + ty*4 + i;
    if (row >= Pp) continue;
    float4 o;
    o.x = acc[i][0]; o.y = acc[i][1]; o.z = acc[i][2]; o.w = acc[i][3];
    *(float4*)(C + (size_t)row*SNP + n0 + tx*4) = o;
  }
}

// ---------------------------------------------------------------- threefry noise
__device__ __forceinline__ unsigned rotl32(unsigned x, int r){ return (x<<r)|(x>>(32-r)); }

__device__ float tf_normal(unsigned idx)
{
  unsigned x0 = 0u;
  unsigned x1 = idx;
  const unsigned ks[3] = {0u, 42u, 0u ^ 42u ^ 0x1BD11BDAu};
  x0 += ks[0]; x1 += ks[1];
  const int rotA[4] = {13,15,26,6};
  const int rotB[4] = {17,29,16,24};
  #pragma unroll
  for (int i=0;i<5;i++){
    #pragma unroll
    for (int q=0;q<4;q++){
      int rr = (i&1) ? rotB[q] : rotA[q];
      x0 += x1; x1 = rotl32(x1, rr); x1 ^= x0;
    }
    x0 += ks[(i+1)%3];
    x1 += ks[(i+2)%3] + (unsigned)(i+1);
  }
  unsigned bits = x0 ^ x1;
  float f = __uint_as_float((bits >> 9) | 0x3f800000u) - 1.0f;
  const float lo = -0.99999994f;
  float u = f * 2.0f + lo;
  u = fmaxf(lo, u);
  float w = -log1pf(-u*u);
  float p;
  if (w < 5.0f) {
    w -= 2.5f;
    p = 2.81022636e-08f;
    p = fmaf(p, w, 3.43273939e-07f);
    p = fmaf(p, w, -3.5233877e-06f);
    p = fmaf(p, w, -4.39150654e-06f);
    p = fmaf(p, w, 0.00021858087f);
    p = fmaf(p, w, -0.00125372503f);
    p = fmaf(p, w, -0.00417768164f);
    p = fmaf(p, w, 0.246640727f);
    p = fmaf(p, w, 1.50140941f);
  } else {
    w = sqrtf(w) - 3.0f;
    p = -0.000200214257f;
    p = fmaf(p, w, 0.000100950558f);
    p = fmaf(p, w, 0.00134934322f);
    p = fmaf(p, w, -0.00367342844f);
    p = fmaf(p, w, 0.00573950773f);
    p = fmaf(p, w, -0.0076224613f);
    p = fmaf(p, w, 0.00943887047f);
    p = fmaf(p, w, 1.00167406f);
    p = fmaf(p, w, 2.83297682f);
  }
  return 1.4142135623730951f * (p * u);
}

// ---------------------------------------------------------------- finalize (f32)
__global__ __launch_bounds__(512) void final_k(
    const float* __restrict__ score, const float* __restrict__ cur_dist,
    const float* __restrict__ ninf, float* __restrict__ out)
{
  __shared__ float smn[8], smx[8], sm2[8], ss[8];
  const float NM = (float)(50.0/501.0);
  const float C1 = (float)(1.0 - 50.0/501.0);
  int r = blockIdx.x;
  int t = threadIdx.x;
  int wid = t >> 6, lane = t & 63;

  float cd = 0.f;
  float mn = 1e30f, mx = -1e30f;
  if (t < NT) { cd = cur_dist[(size_t)r*NT + t]; mn = cd; mx = cd; }
  #pragma unroll
  for (int off=32; off>=1; off>>=1){
    mn = fminf(mn, __shfl_xor(mn, off));
    mx = fmaxf(mx, __shfl_xor(mx, off));
  }
  if (lane == 0){ smn[wid] = mn; smx[wid] = mx; }
  __syncthreads();
  float dmin = smn[0], dmax = smx[0];
  #pragma unroll
  for (int i=1;i<8;i++){ dmin = fminf(dmin, smn[i]); dmax = fmaxf(dmax, smx[i]); }

  float sval = -1e30f;
  if (t < NT) {
    float nd = (cd - dmin) / (dmax - dmin + 1e-6f);
    float z  = tf_normal((unsigned)r*501u + (unsigned)t);
    float s  = score[(size_t)r*SNP + t] - C1*logf(nd + 1e-6f) + (z*0.2f + 0.5f)*NM;
    sval = 10.0f*tanhf(s) + ninf[(size_t)r*NT + t];
  }
  float mv = sval;
  #pragma unroll
  for (int off=32; off>=1; off>>=1) mv = fmaxf(mv, __shfl_xor(mv, off));
  if (lane == 0) sm2[wid] = mv;
  __syncthreads();
  float smax = sm2[0];
  #pragma unroll
  for (int i=1;i<8;i++) smax = fmaxf(smax, sm2[i]);

  float e = (t < NT) ? expf(sval - smax) : 0.f;
  float sv = e;
  #pragma unroll
  for (int off=32; off>=1; off>>=1) sv += __shfl_xor(sv, off);
  if (lane == 0) ss[wid] = sv;
  __syncthreads();
  float ssum = ss[0];
  #pragma unroll
  for (int i=1;i<8;i++) ssum += ss[i];

  if (t < NT) out[(size_t)r*NT + t] = e / ssum;
}

// ---------------------------------------------------------------- launch
extern "C" void kernel_launch(void* const* d_in, const int* in_sizes, int n_in,
                              void* d_out, int out_size, void* d_ws, size_t ws_size,
                              hipStream_t stream)
{
  (void)in_sizes; (void)n_in; (void)out_size; (void)ws_size;
  const float* depot_xy    = (const float*)d_in[0];
  const float* node_xy     = (const float*)d_in[1];
  const float* node_demand = (const float*)d_in[2];
  const float* loadv       = (const float*)d_in[3];
  const float* cur_dist    = (const float*)d_in[4];
  const float* ninf        = (const float*)d_in[5];
  const int*   cur_node    = (const int*)d_in[6];
  const float* emb_depot_w = (const float*)d_in[7];
  const float* emb_depot_b = (const float*)d_in[8];
  const float* emb_node_w  = (const float*)d_in[9];
  const float* emb_node_b  = (const float*)d_in[10];
  const float* enc_wq      = (const float*)d_in[11];
  const float* enc_wk      = (const float*)d_in[12];
  const float* enc_wv      = (const float*)d_in[13];
  const float* enc_comb_w  = (const float*)d_in[14];
  const float* enc_comb_b  = (const float*)d_in[15];
  const float* enc_ff1_w   = (const float*)d_in[16];
  const float* enc_ff1_b   = (const float*)d_in[17];
  const float* enc_ff2_w   = (const float*)d_in[18];
  const float* enc_ff2_b   = (const float*)d_in[19];
  const float* dec_wq_last = (const float*)d_in[20];
  const float* dec_wk      = (const float*)d_in[21];
  const float* dec_wv      = (const float*)d_in[22];
  const float* dec_comb_w  = (const float*)d_in[23];
  const float* dec_comb_b  = (const float*)d_in[24];
  const float* dec_cap_w   = (const float*)d_in[25];
  const float* dec_ff1_w   = (const float*)d_in[26];
  const float* dec_ff1_b   = (const float*)d_in[27];
  const float* dec_ff2_w   = (const float*)d_in[28];
  const float* dec_ff2_b   = (const float*)d_in[29];

  float* ws = (float*)d_ws;
  const size_t SZ = (size_t)Mtok*Ee;   // 1,026,048
  float* xb    = ws + 0*SZ;
  float* qkvb  = ws + 1*SZ;            // enc QKV [Mtok][384]; dec KV [Mtok][256]
  float* atb   = ws + 4*SZ;            // comb input; dec qref
  float* o1b   = ws + 5*SZ;            // part_l; comb out; score
  float* ffb   = ws + 6*SZ;            // FF scratch (4*SZ); part_o; xT
  float* encPk = ws + 10*SZ;
  float* decPk = encPk + ENCP;
  float* part_o  = ffb;                // SPLIT*128*NT*16 = 4*SZ exactly
  float* part_l  = o1b;                // SPLIT*128*NT < SZ
  float* dpart_o = ffb;
  float* dpart_l = o1b;
  float* encl  = qkvb + 2*SZ;
  float* qdec  = encl + 204800;
  float* mhb   = qdec + 204800;
  float* qrefb = atb;
  float* ffh2  = ffb;
  float* xTb   = ffb;
  float* scoreb= o1b;

  pack_k<<<(ENCP + DECP + 255)/256, 256, 0, stream>>>(
      enc_wq, enc_wk, enc_wv, dec_wk, dec_wv, encPk, decPk);

  embed_k<<<(Mtok*Ee + 255)/256, 256, 0, stream>>>(
      depot_xy, node_xy, node_demand, emb_depot_w, emb_depot_b,
      emb_node_w, emb_node_b, xb);

  dim3 gqkv((Mtok + 63)/64, 384/64);
  dim3 g128((Mtok + 63)/64, Ee/64);
  dim3 gff ((Mtok + 63)/64, Ff/64);
  const int gcomb = (128*NT*16 + 255)/256;
  for (int l = 0; l < Ll; ++l) {
    gemm_k<<<gqkv, 256, 0, stream>>>(xb, encPk + (size_t)l*128*384, nullptr, nullptr, qkvb, Mtok, 384, Ee, 0);
    attn_enc_k<<<Bb*Hh*SPLIT, 256, 0, stream>>>(qkvb, part_o, part_l);
    attn_comb_k<<<gcomb, 256, 0, stream>>>(part_o, part_l, atb);
    gemm_k<<<g128, 256, 0, stream>>>(atb, enc_comb_w + (size_t)l*Ee*Ee, enc_comb_b + l*Ee, xb, o1b, Mtok, Ee, Ee, 0);
    gemm_k<<<gff, 256, 0, stream>>>(o1b, enc_ff1_w + (size_t)l*Ee*Ff, enc_ff1_b + l*Ff, nullptr, ffb, Mtok, Ff, Ee, 1);
    gemm_k<<<g128, 256, 0, stream>>>(ffb, enc_ff2_w + (size_t)l*Ff*Ee, enc_ff2_b + l*Ee, o1b, xb, Mtok, Ee, Ff, 0);
  }

  // decoder
  dim3 gkv((Mtok + 63)/64, 256/64);
  gemm_k<<<gkv, 256, 0, stream>>>(xb, decPk, nullptr, nullptr, qkvb, Mtok, 256, Ee, 0);
  decq_k<<<PR, 128, 0, stream>>>(xb, cur_node, loadv, dec_wq_last, qdec, encl);
  attn_dec_k<<<Bb*Hh*DSPLIT, 128, 0, stream>>>(qdec, qkvb, ninf, dpart_o, dpart_l);
  dec_comb_k<<<PR, 128, 0, stream>>>(dpart_o, dpart_l, dec_comb_w, dec_comb_b, encl, loadv, dec_cap_w, mhb);
  dim3 gd1((PR + 63)/64, Ff/64);
  gemm_k<<<gd1, 256, 0, stream>>>(mhb, dec_ff1_w, dec_ff1_b, nullptr, ffh2, PR, Ff, Ee, 1);
  dim3 gd2((PR + 63)/64, Ee/64);
  gemm_k<<<gd2, 256, 0, stream>>>(ffh2, dec_ff2_w, dec_ff2_b, mhb, qrefb, PR, Ee, Ff, 0);
  dim3 gxt(16, 4, 16);
  xt_k<<<gxt, 256, 0, stream>>>(xb, xTb);
  dim3 gsc(2, 8, 16);
  score_gemm_k<<<gsc, 256, 0, stream>>>(qrefb, xTb, scoreb);
  final_k<<<PR, 512, 0, stream>>>(scoreb, cur_dist, ninf, (float*)d_out);
}

// Round 17
// 884.616 us; speedup vs baseline: 1.1084x; 1.0011x over previous
//
#include <hip/hip_runtime.h>
#include <math.h>

#define Bb 16
#define Nn 500
#define NT 501
#define Pp 100
#define Ee 128
#define Hh 8
#define Dd 16
#define Ff 512
#define Ll 6
#define Mtok (Bb*NT)   // 8016
#define PR (Bb*Pp)     // 1600
#define TJ 32          // attn_enc KV tile rows
#define DSPLIT 16      // decoder KV-split
#define DSEG 32
#define ENCP (6*128*384)
#define DECP (128*256)
#define SNP 512        // padded score row stride

// ---------------------------------------------------------------- weight packing
__global__ __launch_bounds__(256) void pack_k(
    const float* __restrict__ ewq, const float* __restrict__ ewk, const float* __restrict__ ewv,
    const float* __restrict__ dwk, const float* __restrict__ dwv,
    float* __restrict__ encP, float* __restrict__ decP)
{
  int i = blockIdx.x*256 + threadIdx.x;
  if (i < ENCP) {
    int l = i / (128*384); int rem = i - l*128*384; int k = rem / 384; int n = rem - k*384;
    float v;
    if (n < 128)      v = ewq[((size_t)l*128 + k)*128 + n];
    else if (n < 256) v = ewk[((size_t)l*128 + k)*128 + (n-128)];
    else              v = ewv[((size_t)l*128 + k)*128 + (n-256)];
    encP[i] = v;
  } else {
    int j = i - ENCP;
    if (j < DECP) {
      int k = j >> 8; int n = j & 255;
      decP[j] = (n < 128) ? dwk[k*128 + n] : dwv[k*128 + (n-128)];
    }
  }
}

// ---------------------------------------------------------------- embed
__global__ __launch_bounds__(256) void embed_k(
    const float* __restrict__ depot_xy, const float* __restrict__ node_xy,
    const float* __restrict__ node_demand,
    const float* __restrict__ wD, const float* __restrict__ bD,
    const float* __restrict__ wN, const float* __restrict__ bN,
    float* __restrict__ x)
{
  int t = blockIdx.x*256 + threadIdx.x;
  if (t >= Mtok*Ee) return;
  int e   = t & (Ee-1);
  int tok = t >> 7;
  int b   = tok / NT;
  int n   = tok - b*NT;
  float v;
  if (n == 0) {
    v = depot_xy[b*2+0]*wD[0*Ee+e] + depot_xy[b*2+1]*wD[1*Ee+e] + bD[e];
  } else {
    int nn = n - 1;
    float c0 = node_xy[(b*Nn + nn)*2 + 0];
    float c1 = node_xy[(b*Nn + nn)*2 + 1];
    float c2 = node_demand[b*Nn + nn];
    v = c0*wN[0*Ee+e] + c1*wN[1*Ee+e] + c2*wN[2*Ee+e] + bN[e];
  }
  x[(size_t)tok*Ee + e] = v;
}

// ---------------------------------------------------------------- GEMM (f32, proven)
__global__ __launch_bounds__(256) void gemm_k(
    const float* __restrict__ A, const float* __restrict__ W,
    const float* __restrict__ bias, const float* __restrict__ res,
    float* __restrict__ C, int M, int N, int K, int relu)
{
  __shared__ __align__(16) float As[2][16][68];
  __shared__ __align__(16) float Bs[2][16][68];
  int tid = threadIdx.x;
  int tx = tid & 15, ty = tid >> 4;
  int m0 = blockIdx.x * 64, n0 = blockIdx.y * 64;
  float acc[4][4];
  #pragma unroll
  for (int i=0;i<4;i++)
    #pragma unroll
    for (int j=0;j<4;j++) acc[i][j] = 0.f;

  int ar = tid >> 2;
  int ak = (tid & 3) << 2;
  int br = tid >> 4;
  int bc = (tid & 15) << 2;

  const float* Ap = A + (size_t)(m0 + ar)*K + ak;
  const float* Wp = W + (size_t)br*N + n0 + bc;
  bool aok = (m0 + ar) < M;

  float4 av = aok ? *(const float4*)(Ap) : make_float4(0.f,0.f,0.f,0.f);
  float4 wv = *(const float4*)(Wp);

  int nk = K >> 4;
  for (int t = 0; t < nk; ++t) {
    int cur = t & 1;
    As[cur][ak+0][ar] = av.x; As[cur][ak+1][ar] = av.y;
    As[cur][ak+2][ar] = av.z; As[cur][ak+3][ar] = av.w;
    *(float4*)(&Bs[cur][br][bc]) = wv;
    __syncthreads();
    if (t+1 < nk) {
      av = aok ? *(const float4*)(Ap + (t+1)*16) : make_float4(0.f,0.f,0.f,0.f);
      wv = *(const float4*)(Wp + (size_t)(t+1)*16*N);
    }
    #pragma unroll
    for (int k=0;k<16;k++){
      float4 a4 = *(const float4*)(&As[cur][k][ty*4]);
      float4 b4 = *(const float4*)(&Bs[cur][k][tx*4]);
      float avv[4] = {a4.x,a4.y,a4.z,a4.w};
      float bvv[4] = {b4.x,b4.y,b4.z,b4.w};
      #pragma unroll
      for (int i=0;i<4;i++)
        #pragma unroll
        for (int j=0;j<4;j++)
          acc[i][j] = fmaf(avv[i], bvv[j], acc[i][j]);
    }
  }

  float4 bv = make_float4(0.f,0.f,0.f,0.f);
  if (bias) bv = *(const float4*)(bias + n0 + tx*4);
  #pragma unroll
  for (int i=0;i<4;i++){
    int row = m0 + ty*4 + i;
    if (row >= M) continue;
    float4 o;
    o.x = acc[i][0] + bv.x; o.y = acc[i][1] + bv.y;
    o.z = acc[i][2] + bv.z; o.w = acc[i][3] + bv.w;
    if (relu){ o.x=fmaxf(o.x,0.f); o.y=fmaxf(o.y,0.f); o.z=fmaxf(o.z,0.f); o.w=fmaxf(o.w,0.f); }
    if (res){
      float4 rv = *(const float4*)(res + (size_t)row*N + n0 + tx*4);
      o.x += rv.x; o.y += rv.y; o.z += rv.z; o.w += rv.w;
    }
    *(float4*)(C + (size_t)row*N + n0 + tx*4) = o;
  }
}

// ---------------------------------------------------------------- attention
__device__ __forceinline__ float dot4(float4 a, float4 b){
  return fmaf(a.x,b.x, fmaf(a.y,b.y, fmaf(a.z,b.z, a.w*b.w)));
}

// encoder self-attention v6: 256 threads, 2 queries/thread, runtime KV-split,
// s-major block order (s-blocks sharing a Q slice colocate on one XCD).
__global__ __launch_bounds__(256, 1) void attn_enc_k(
    const float* __restrict__ QKV, float* __restrict__ part_o,
    float* __restrict__ part_l, int ksegsz)
{
  int blk = blockIdx.x;            // s*128 + bh
  int s  = blk >> 7;
  int bh = blk & 127;
  int h  = bh & (Hh-1);
  int b  = bh >> 3;
  int tid = threadIdx.x;
  int p0 = tid;
  int p1 = tid + 256;
  const int klo = s*ksegsz;
  int kseg = NT - klo; if (kseg > ksegsz) kseg = ksegsz;

  __shared__ __align__(16) float4 Ks[2][TJ][4];
  __shared__ __align__(16) float4 Vs[2][TJ][4];

  int row = (tid >> 2) & 31;
  int lc  = tid & 3;
  bool isV = tid >= 128;
  const int kvoff = isV ? 256 : 128;

  bool vbq = p1 < NT;

  const float4* qp0 = (const float4*)(QKV + ((size_t)(b*NT + p0))*384 + h*Dd);
  float4 qa0=qp0[0], qa1=qp0[1], qa2=qp0[2], qa3=qp0[3];
  float4 qb0,qb1,qb2,qb3;
  if (vbq) {
    const float4* qp1 = (const float4*)(QKV + ((size_t)(b*NT + p1))*384 + h*Dd);
    qb0=qp1[0]; qb1=qp1[1]; qb2=qp1[2]; qb3=qp1[3];
  } else {
    qb0=qb1=qb2=qb3=make_float4(0,0,0,0);
  }

  if (row < kseg) {
    float4 v = *((const float4*)(QKV + ((size_t)(b*NT + klo + row))*384 + kvoff + h*Dd) + lc);
    if (isV) Vs[0][row][lc] = v; else Ks[0][row][lc] = v;
  }
  __syncthreads();

  float lA = 0.f, lB = 0.f;
  float4 oA0=make_float4(0,0,0,0), oA1=oA0, oA2=oA0, oA3=oA0;
  float4 oB0=oA0, oB1=oA0, oB2=oA0, oB3=oA0;
  const int ntiles = (kseg + TJ - 1)/TJ;
  int buf = 0;

  for (int t = 0; t < ntiles; ++t) {
    int j0 = t*TJ;
    if (t+1 < ntiles) {
      int jj = j0 + TJ + row;
      if (jj < kseg) {
        float4 v = *((const float4*)(QKV + ((size_t)(b*NT + klo + jj))*384 + kvoff + h*Dd) + lc);
        if (isV) Vs[buf^1][row][lc] = v; else Ks[buf^1][row][lc] = v;
      }
    }
    int jend = kseg - j0; if (jend > TJ) jend = TJ;

    #pragma unroll 2
    for (int jj = 0; jj < jend; ++jj) {
      float4 k0=Ks[buf][jj][0], k1=Ks[buf][jj][1], k2=Ks[buf][jj][2], k3=Ks[buf][jj][3];
      float sA = (dot4(qa0,k0)+dot4(qa1,k1)) + (dot4(qa2,k2)+dot4(qa3,k3));
      float sB = (dot4(qb0,k0)+dot4(qb1,k1)) + (dot4(qb2,k2)+dot4(qb3,k3));
      float wA = __expf(sA*0.25f);
      float wB = __expf(sB*0.25f);
      lA += wA; lB += wB;
      float4 v0=Vs[buf][jj][0], v1=Vs[buf][jj][1], v2=Vs[buf][jj][2], v3=Vs[buf][jj][3];
      oA0.x=fmaf(wA,v0.x,oA0.x); oA0.y=fmaf(wA,v0.y,oA0.y); oA0.z=fmaf(wA,v0.z,oA0.z); oA0.w=fmaf(wA,v0.w,oA0.w);
      oA1.x=fmaf(wA,v1.x,oA1.x); oA1.y=fmaf(wA,v1.y,oA1.y); oA1.z=fmaf(wA,v1.z,oA1.z); oA1.w=fmaf(wA,v1.w,oA1.w);
      oA2.x=fmaf(wA,v2.x,oA2.x); oA2.y=fmaf(wA,v2.y,oA2.y); oA2.z=fmaf(wA,v2.z,oA2.z); oA2.w=fmaf(wA,v2.w,oA2.w);
      oA3.x=fmaf(wA,v3.x,oA3.x); oA3.y=fmaf(wA,v3.y,oA3.y); oA3.z=fmaf(wA,v3.z,oA3.z); oA3.w=fmaf(wA,v3.w,oA3.w);
      oB0.x=fmaf(wB,v0.x,oB0.x); oB0.y=fmaf(wB,v0.y,oB0.y); oB0.z=fmaf(wB,v0.z,oB0.z); oB0.w=fmaf(wB,v0.w,oB0.w);
      oB1.x=fmaf(wB,v1.x,oB1.x); oB1.y=fmaf(wB,v1.y,oB1.y); oB1.z=fmaf(wB,v1.z,oB1.z); oB1.w=fmaf(wB,v1.w,oB1.w);
      oB2.x=fmaf(wB,v2.x,oB2.x); oB2.y=fmaf(wB,v2.y,oB2.y); oB2.z=fmaf(wB,v2.z,oB2.z); oB2.w=fmaf(wB,v2.w,oB2.w);
      oB3.x=fmaf(wB,v3.x,oB3.x); oB3.y=fmaf(wB,v3.y,oB3.y); oB3.z=fmaf(wB,v3.z,oB3.z); oB3.w=fmaf(wB,v3.w,oB3.w);
    }
    __syncthreads();
    buf ^= 1;
  }

  size_t r0 = ((size_t)s*128 + bh)*NT + p0;
  float4* po0 = (float4*)(part_o + r0*16);
  po0[0]=oA0; po0[1]=oA1; po0[2]=oA2; po0[3]=oA3;
  part_l[r0] = lA;
  if (vbq) {
    size_t r1 = ((size_t)s*128 + bh)*NT + p1;
    float4* po1 = (float4*)(part_o + r1*16);
    po1[0]=oB0; po1[1]=oB1; po1[2]=oB2; po1[3]=oB3;
    part_l[r1] = lB;
  }
}

// combine nsplit partials (plain sums) -> O[b,q,h,d]
__global__ __launch_bounds__(256) void attn_comb_k(
    const float* __restrict__ part_o, const float* __restrict__ part_l,
    float* __restrict__ O, int nsplit)
{
  int t = blockIdx.x*256 + threadIdx.x;
  if (t >= 128*NT*16) return;
  int d  = t & 15;
  int rq = t >> 4;
  int q  = rq % NT;
  int bh = rq / NT;
  int h = bh & 7, b = bh >> 3;
  const size_t R = (size_t)128*NT;
  float L = 0.f, o = 0.f;
  for (int s=0;s<nsplit;s++){
    L += part_l[(size_t)s*R + rq];
    o += part_o[((size_t)s*R + rq)*16 + d];
  }
  O[((size_t)(b*NT + q))*Ee + h*Dd + d] = o / L;
}

// decoder cross-attention: LDS-staged broadcast, DSPLIT=16 segments of 32.
__global__ __launch_bounds__(128) void attn_dec_k(
    const float* __restrict__ Q, const float* __restrict__ KV,
    const float* __restrict__ mask,
    float* __restrict__ part_o, float* __restrict__ part_l)
{
  int blk = blockIdx.x;
  int s  = blk & (DSPLIT-1);
  int bh = blk >> 4;
  int h  = bh & (Hh-1);
  int b  = bh >> 3;
  int klo = s*DSEG;
  int kn  = NT - klo; if (kn > DSEG) kn = DSEG;

  __shared__ __align__(16) float4 Ks[DSEG][4];
  __shared__ __align__(16) float4 Vs[DSEG][4];

  int tid = threadIdx.x;
  for (int i = tid; i < kn*8; i += 128) {
    int row  = i >> 3;
    int q8   = i & 7;
    int quad = q8 & 3;
    int isv  = q8 >> 2;
    float4 v = *(const float4*)(KV + ((size_t)(b*NT + klo + row))*256 + isv*128 + h*Dd + quad*4);
    if (isv) Vs[row][quad] = v; else Ks[row][quad] = v;
  }
  __syncthreads();

  int p = tid;
  if (p >= Pp) return;
  int r = b*Pp + p;
  const float4* qp = (const float4*)(Q + (size_t)r*Ee + h*Dd);
  float4 qa=qp[0], qb=qp[1], qc=qp[2], qd=qp[3];
  const float* mrow = mask + (size_t)r*NT + klo;

  float l = 0.f;
  float4 o0=make_float4(0,0,0,0), o1=o0, o2=o0, o3=o0;
  for (int j=0;j<kn;++j){
    float sc = (dot4(qa,Ks[j][0])+dot4(qb,Ks[j][1])) + (dot4(qc,Ks[j][2])+dot4(qd,Ks[j][3]));
    float w = __expf(sc*0.25f + mrow[j]);
    l += w;
    float4 v0=Vs[j][0],v1=Vs[j][1],v2=Vs[j][2],v3=Vs[j][3];
    o0.x=fmaf(w,v0.x,o0.x); o0.y=fmaf(w,v0.y,o0.y); o0.z=fmaf(w,v0.z,o0.z); o0.w=fmaf(w,v0.w,o0.w);
    o1.x=fmaf(w,v1.x,o1.x); o1.y=fmaf(w,v1.y,o1.y); o1.z=fmaf(w,v1.z,o1.z); o1.w=fmaf(w,v1.w,o1.w);
    o2.x=fmaf(w,v2.x,o2.x); o2.y=fmaf(w,v2.y,o2.y); o2.z=fmaf(w,v2.z,o2.z); o2.w=fmaf(w,v2.w,o2.w);
    o3.x=fmaf(w,v3.x,o3.x); o3.y=fmaf(w,v3.y,o3.y); o3.z=fmaf(w,v3.z,o3.z); o3.w=fmaf(w,v3.w,o3.w);
  }

  size_t rb = ((size_t)s*PR + r)*Hh + h;
  float4* po = (float4*)(part_o + rb*16);
  po[0]=o0; po[1]=o1; po[2]=o2; po[3]=o3;
  part_l[rb] = l;
}

// ---------------------------------------------------------------- decoder small ops
__global__ __launch_bounds__(128) void decq_k(
    const float* __restrict__ x, const int* __restrict__ cur,
    const float* __restrict__ loadv, const float* __restrict__ Wq,
    float* __restrict__ q, float* __restrict__ encl)
{
  __shared__ float row[Ee];
  int r = blockIdx.x, e = threadIdx.x;
  int b = r / Pp;
  int node = cur[r];
  float xv = x[((size_t)(b*NT + node))*Ee + e];
  encl[(size_t)r*Ee + e] = xv;
  row[e] = xv;
  __syncthreads();
  float acc = 0.f;
  #pragma unroll 4
  for (int k=0;k<Ee;k++) acc = fmaf(row[k], Wq[k*128 + e], acc);
  acc = fmaf(loadv[r], Wq[Ee*128 + e], acc);
  q[(size_t)r*128 + e] = acc;
}

__global__ __launch_bounds__(128) void dec_comb_k(
    const float* __restrict__ dpart_o, const float* __restrict__ dpart_l,
    const float* __restrict__ W, const float* __restrict__ bias,
    const float* __restrict__ encl, const float* __restrict__ loadv,
    const float* __restrict__ capw, float* __restrict__ mh)
{
  __shared__ float row[Ee];
  int r = blockIdx.x, e = threadIdx.x;
  int h = e >> 4, d = e & 15;
  const size_t S = (size_t)PR*Hh;
  size_t rb = (size_t)r*Hh + h;
  float L = 0.f, o = 0.f;
  #pragma unroll
  for (int s=0;s<DSPLIT;s++){
    L += dpart_l[(size_t)s*S + rb];
    o += dpart_o[((size_t)s*S + rb)*16 + d];
  }
  row[e] = o / L;
  __syncthreads();
  float acc = 0.f;
  #pragma unroll 4
  for (int k=0;k<Ee;k++) acc = fmaf(row[k], W[k*Ee + e], acc);
  mh[(size_t)r*Ee + e] = acc + bias[e] + encl[(size_t)r*Ee + e] + loadv[r]*capw[e];
}

// ---------------------------------------------------------------- score via batched GEMM
__global__ __launch_bounds__(256) void xt_k(
    const float* __restrict__ x, float* __restrict__ xT)
{
  __shared__ float T[32][33];
  int n0 = blockIdx.x * 32;
  int k0 = blockIdx.y * 32;
  int b  = blockIdx.z;
  int t  = threadIdx.x;
  int row = t >> 3;
  int c4  = (t & 7) << 2;

  int n = n0 + row;
  float4 v = make_float4(0.f,0.f,0.f,0.f);
  if (n < NT) v = *(const float4*)(x + ((size_t)(b*NT + n))*Ee + k0 + c4);
  T[c4+0][row] = v.x; T[c4+1][row] = v.y; T[c4+2][row] = v.z; T[c4+3][row] = v.w;
  __syncthreads();

  const float SC = 0.08838834764831845f;
  float4 o;
  o.x = T[row][c4+0]*SC; o.y = T[row][c4+1]*SC;
  o.z = T[row][c4+2]*SC; o.w = T[row][c4+3]*SC;
  *(float4*)(xT + ((size_t)(b*Ee + k0 + row))*SNP + n0 + c4) = o;
}

__global__ __launch_bounds__(256) void score_gemm_k(
    const float* __restrict__ qref, const float* __restrict__ xT,
    float* __restrict__ score)
{
  __shared__ __align__(16) float As[2][16][68];
  __shared__ __align__(16) float Bs[2][16][68];
  int tid = threadIdx.x;
  int tx = tid & 15, ty = tid >> 4;
  int m0 = blockIdx.x * 64;
  int n0 = blockIdx.y * 64;
  int b  = blockIdx.z;

  const float* A = qref + (size_t)b*Pp*Ee;
  const float* W = xT   + (size_t)b*Ee*SNP;
  float*       C = score + (size_t)b*Pp*SNP;

  float acc[4][4];
  #pragma unroll
  for (int i=0;i<4;i++)
    #pragma unroll
    for (int j=0;j<4;j++) acc[i][j] = 0.f;

  int ar = tid >> 2;
  int ak = (tid & 3) << 2;
  int br = tid >> 4;
  int bc = (tid & 15) << 2;

  const float* Ap = A + (size_t)(m0 + ar)*Ee + ak;
  const float* Wp = W + (size_t)br*SNP + n0 + bc;
  bool aok = (m0 + ar) < Pp;

  float4 av = aok ? *(const float4*)(Ap) : make_float4(0.f,0.f,0.f,0.f);
  float4 wv = *(const float4*)(Wp);

  for (int t = 0; t < 8; ++t) {
    int cur = t & 1;
    As[cur][ak+0][ar] = av.x; As[cur][ak+1][ar] = av.y;
    As[cur][ak+2][ar] = av.z; As[cur][ak+3][ar] = av.w;
    *(float4*)(&Bs[cur][br][bc]) = wv;
    __syncthreads();
    if (t+1 < 8) {
      av = aok ? *(const float4*)(Ap + (t+1)*16) : make_float4(0.f,0.f,0.f,0.f);
      wv = *(const float4*)(Wp + (size_t)(t+1)*16*SNP);
    }
    #pragma unroll
    for (int k=0;k<16;k++){
      float4 a4 = *(const float4*)(&As[cur][k][ty*4]);
      float4 b4 = *(const float4*)(&Bs[cur][k][tx*4]);
      float avv[4] = {a4.x,a4.y,a4.z,a4.w};
      float bvv[4] = {b4.x,b4.y,b4.z,b4.w};
      #pragma unroll
      for (int i=0;i<4;i++)
        #pragma unroll
        for (int j=0;j<4;j++)
          acc[i][j] = fmaf(avv[i], bvv[j], acc[i][j]);
    }
    __syncthreads();
  }

  #pragma unroll
  for (int i=0;i<4;i++){
    int row = m0 + ty*4 + i;
    if (row >= Pp) continue;
    float4 o;
    o.x = acc[i][0]; o.y = acc[i][1]; o.z = acc[i][2]; o.w = acc[i][3];
    *(float4*)(C + (size_t)row*SNP + n0 + tx*4) = o;
  }
}

// ---------------------------------------------------------------- threefry noise
__device__ __forceinline__ unsigned rotl32(unsigned x, int r){ return (x<<r)|(x>>(32-r)); }

__device__ float tf_normal(unsigned idx)
{
  unsigned x0 = 0u;
  unsigned x1 = idx;
  const unsigned ks[3] = {0u, 42u, 0u ^ 42u ^ 0x1BD11BDAu};
  x0 += ks[0]; x1 += ks[1];
  const int rotA[4] = {13,15,26,6};
  const int rotB[4] = {17,29,16,24};
  #pragma unroll
  for (int i=0;i<5;i++){
    #pragma unroll
    for (int q=0;q<4;q++){
      int rr = (i&1) ? rotB[q] : rotA[q];
      x0 += x1; x1 = rotl32(x1, rr); x1 ^= x0;
    }
    x0 += ks[(i+1)%3];
    x1 += ks[(i+2)%3] + (unsigned)(i+1);
  }
  unsigned bits = x0 ^ x1;
  float f = __uint_as_float((bits >> 9) | 0x3f800000u) - 1.0f;
  const float lo = -0.99999994f;
  float u = f * 2.0f + lo;
  u = fmaxf(lo, u);
  float w = -log1pf(-u*u);
  float p;
  if (w < 5.0f) {
    w -= 2.5f;
    p = 2.81022636e-08f;
    p = fmaf(p, w, 3.43273939e-07f);
    p = fmaf(p, w, -3.5233877e-06f);
    p = fmaf(p, w, -4.39150654e-06f);
    p = fmaf(p, w, 0.00021858087f);
    p = fmaf(p, w, -0.00125372503f);
    p = fmaf(p, w, -0.00417768164f);
    p = fmaf(p, w, 0.246640727f);
    p = fmaf(p, w, 1.50140941f);
  } else {
    w = sqrtf(w) - 3.0f;
    p = -0.000200214257f;
    p = fmaf(p, w, 0.000100950558f);
    p = fmaf(p, w, 0.00134934322f);
    p = fmaf(p, w, -0.00367342844f);
    p = fmaf(p, w, 0.00573950773f);
    p = fmaf(p, w, -0.0076224613f);
    p = fmaf(p, w, 0.00943887047f);
    p = fmaf(p, w, 1.00167406f);
    p = fmaf(p, w, 2.83297682f);
  }
  return 1.4142135623730951f * (p * u);
}

// ---------------------------------------------------------------- finalize (f32)
__global__ __launch_bounds__(512) void final_k(
    const float* __restrict__ score, const float* __restrict__ cur_dist,
    const float* __restrict__ ninf, float* __restrict__ out)
{
  __shared__ float smn[8], smx[8], sm2[8], ss[8];
  const float NM = (float)(50.0/501.0);
  const float C1 = (float)(1.0 - 50.0/501.0);
  int r = blockIdx.x;
  int t = threadIdx.x;
  int wid = t >> 6, lane = t & 63;

  float cd = 0.f;
  float mn = 1e30f, mx = -1e30f;
  if (t < NT) { cd = cur_dist[(size_t)r*NT + t]; mn = cd; mx = cd; }
  #pragma unroll
  for (int off=32; off>=1; off>>=1){
    mn = fminf(mn, __shfl_xor(mn, off));
    mx = fmaxf(mx, __shfl_xor(mx, off));
  }
  if (lane == 0){ smn[wid] = mn; smx[wid] = mx; }
  __syncthreads();
  float dmin = smn[0], dmax = smx[0];
  #pragma unroll
  for (int i=1;i<8;i++){ dmin = fminf(dmin, smn[i]); dmax = fmaxf(dmax, smx[i]); }

  float sval = -1e30f;
  if (t < NT) {
    float nd = (cd - dmin) / (dmax - dmin + 1e-6f);
    float z  = tf_normal((unsigned)r*501u + (unsigned)t);
    float s  = score[(size_t)r*SNP + t] - C1*logf(nd + 1e-6f) + (z*0.2f + 0.5f)*NM;
    sval = 10.0f*tanhf(s) + ninf[(size_t)r*NT + t];
  }
  float mv = sval;
  #pragma unroll
  for (int off=32; off>=1; off>>=1) mv = fmaxf(mv, __shfl_xor(mv, off));
  if (lane == 0) sm2[wid] = mv;
  __syncthreads();
  float smax = sm2[0];
  #pragma unroll
  for (int i=1;i<8;i++) smax = fmaxf(smax, sm2[i]);

  float e = (t < NT) ? expf(sval - smax) : 0.f;
  float sv = e;
  #pragma unroll
  for (int off=32; off>=1; off>>=1) sv += __shfl_xor(sv, off);
  if (lane == 0) ss[wid] = sv;
  __syncthreads();
  float ssum = ss[0];
  #pragma unroll
  for (int i=1;i<8;i++) ssum += ss[i];

  if (t < NT) out[(size_t)r*NT + t] = e / ssum;
}

// ---------------------------------------------------------------- launch
extern "C" void kernel_launch(void* const* d_in, const int* in_sizes, int n_in,
                              void* d_out, int out_size, void* d_ws, size_t ws_size,
                              hipStream_t stream)
{
  (void)in_sizes; (void)n_in; (void)out_size;
  const float* depot_xy    = (const float*)d_in[0];
  const float* node_xy     = (const float*)d_in[1];
  const float* node_demand = (const float*)d_in[2];
  const float* loadv       = (const float*)d_in[3];
  const float* cur_dist    = (const float*)d_in[4];
  const float* ninf        = (const float*)d_in[5];
  const int*   cur_node    = (const int*)d_in[6];
  const float* emb_depot_w = (const float*)d_in[7];
  const float* emb_depot_b = (const float*)d_in[8];
  const float* emb_node_w  = (const float*)d_in[9];
  const float* emb_node_b  = (const float*)d_in[10];
  const float* enc_wq      = (const float*)d_in[11];
  const float* enc_wk      = (const float*)d_in[12];
  const float* enc_wv      = (const float*)d_in[13];
  const float* enc_comb_w  = (const float*)d_in[14];
  const float* enc_comb_b  = (const float*)d_in[15];
  const float* enc_ff1_w   = (const float*)d_in[16];
  const float* enc_ff1_b   = (const float*)d_in[17];
  const float* enc_ff2_w   = (const float*)d_in[18];
  const float* enc_ff2_b   = (const float*)d_in[19];
  const float* dec_wq_last = (const float*)d_in[20];
  const float* dec_wk      = (const float*)d_in[21];
  const float* dec_wv      = (const float*)d_in[22];
  const float* dec_comb_w  = (const float*)d_in[23];
  const float* dec_comb_b  = (const float*)d_in[24];
  const float* dec_cap_w   = (const float*)d_in[25];
  const float* dec_ff1_w   = (const float*)d_in[26];
  const float* dec_ff1_b   = (const float*)d_in[27];
  const float* dec_ff2_w   = (const float*)d_in[28];
  const float* dec_ff2_b   = (const float*)d_in[29];

  float* ws = (float*)d_ws;
  const size_t SZ = (size_t)Mtok*Ee;   // 1,026,048
  float* xb    = ws + 0*SZ;
  float* qkvb  = ws + 1*SZ;            // enc QKV [Mtok][384]; dec KV [Mtok][256]
  float* atb   = ws + 4*SZ;            // comb input; dec qref
  float* o1b   = ws + 5*SZ;            // part_l; comb out; score
  float* ffb   = ws + 6*SZ;            // FF scratch (4*SZ); part_o (SPLIT4); xT
  float* encPk = ws + 10*SZ;
  float* decPk = encPk + ENCP;
  float* ext   = decPk + DECP;         // extra region for SPLIT8 partials

  // choose encoder KV-split by available workspace
  const size_t need8 = (size_t)(10*SZ + ENCP + DECP + 8*SZ) * sizeof(float);
  int ESPLIT, EKSEG;
  float* part_o;
  if (ws_size >= need8) { ESPLIT = 8; EKSEG = 63;  part_o = ext; }
  else                  { ESPLIT = 4; EKSEG = 126; part_o = ffb; }
  float* part_l  = o1b;
  float* dpart_o = ffb;
  float* dpart_l = o1b;
  float* encl  = qkvb + 2*SZ;
  float* qdec  = encl + 204800;
  float* mhb   = qdec + 204800;
  float* qrefb = atb;
  float* ffh2  = ffb;
  float* xTb   = ffb;
  float* scoreb= o1b;

  pack_k<<<(ENCP + DECP + 255)/256, 256, 0, stream>>>(
      enc_wq, enc_wk, enc_wv, dec_wk, dec_wv, encPk, decPk);

  embed_k<<<(Mtok*Ee + 255)/256, 256, 0, stream>>>(
      depot_xy, node_xy, node_demand, emb_depot_w, emb_depot_b,
      emb_node_w, emb_node_b, xb);

  dim3 gqkv((Mtok + 63)/64, 384/64);
  dim3 g128((Mtok + 63)/64, Ee/64);
  dim3 gff ((Mtok + 63)/64, Ff/64);
  const int gcomb = (128*NT*16 + 255)/256;
  for (int l = 0; l < Ll; ++l) {
    gemm_k<<<gqkv, 256, 0, stream>>>(xb, encPk + (size_t)l*128*384, nullptr, nullptr, qkvb, Mtok, 384, Ee, 0);
    attn_enc_k<<<ESPLIT*128, 256, 0, stream>>>(qkvb, part_o, part_l, EKSEG);
    attn_comb_k<<<gcomb, 256, 0, stream>>>(part_o, part_l, atb, ESPLIT);
    gemm_k<<<g128, 256, 0, stream>>>(atb, enc_comb_w + (size_t)l*Ee*Ee, enc_comb_b + l*Ee, xb, o1b, Mtok, Ee, Ee, 0);
    gemm_k<<<gff, 256, 0, stream>>>(o1b, enc_ff1_w + (size_t)l*Ee*Ff, enc_ff1_b + l*Ff, nullptr, ffb, Mtok, Ff, Ee, 1);
    gemm_k<<<g128, 256, 0, stream>>>(ffb, enc_ff2_w + (size_t)l*Ff*Ee, enc_ff2_b + l*Ee, o1b, xb, Mtok, Ee, Ff, 0);
  }

  // decoder
  dim3 gkv((Mtok + 63)/64, 256/64);
  gemm_k<<<gkv, 256, 0, stream>>>(xb, decPk, nullptr, nullptr, qkvb, Mtok, 256, Ee, 0);
  decq_k<<<PR, 128, 0, stream>>>(xb, cur_node, loadv, dec_wq_last, qdec, encl);
  attn_dec_k<<<Bb*Hh*DSPLIT, 128, 0, stream>>>(qdec, qkvb, ninf, dpart_o, dpart_l);
  dec_comb_k<<<PR, 128, 0, stream>>>(dpart_o, dpart_l, dec_comb_w, dec_comb_b, encl, loadv, dec_cap_w, mhb);
  dim3 gd1((PR + 63)/64, Ff/64);
  gemm_k<<<gd1, 256, 0, stream>>>(mhb, dec_ff1_w, dec_ff1_b, nullptr, ffh2, PR, Ff, Ee, 1);
  dim3 gd2((PR + 63)/64, Ee/64);
  gemm_k<<<gd2, 256, 0, stream>>>(ffh2, dec_ff2_w, dec_ff2_b, mhb, qrefb, PR, Ee, Ff, 0);
  dim3 gxt(16, 4, 16);
  xt_k<<<gxt, 256, 0, stream>>>(xb, xTb);
  dim3 gsc(2, 8, 16);
  score_gemm_k<<<gsc, 256, 0, stream>>>(qrefb, xTb, scoreb);
  final_k<<<PR, 512, 0, stream>>>(scoreb, cur_dist, ninf, (float*)d_out);
}

// Round 18
// 870.898 us; speedup vs baseline: 1.1259x; 1.0158x over previous
//
#include <hip/hip_runtime.h>
#include <math.h>

#define Bb 16
#define Nn 500
#define NT 501
#define Pp 100
#define Ee 128
#define Hh 8
#define Dd 16
#define Ff 512
#define Ll 6
#define Mtok (Bb*NT)   // 8016
#define PR (Bb*Pp)     // 1600
#define TJ 32          // attn_enc KV tile rows
#define DSPLIT 16      // decoder KV-split
#define DSEG 32
#define ENCP (6*128*384)
#define DECP (128*256)
#define SNP 512        // padded score row stride

// ---------------------------------------------------------------- weight packing
__global__ __launch_bounds__(256) void pack_k(
    const float* __restrict__ ewq, const float* __restrict__ ewk, const float* __restrict__ ewv,
    const float* __restrict__ dwk, const float* __restrict__ dwv,
    float* __restrict__ encP, float* __restrict__ decP)
{
  int i = blockIdx.x*256 + threadIdx.x;
  if (i < ENCP) {
    int l = i / (128*384); int rem = i - l*128*384; int k = rem / 384; int n = rem - k*384;
    float v;
    if (n < 128)      v = ewq[((size_t)l*128 + k)*128 + n];
    else if (n < 256) v = ewk[((size_t)l*128 + k)*128 + (n-128)];
    else              v = ewv[((size_t)l*128 + k)*128 + (n-256)];
    encP[i] = v;
  } else {
    int j = i - ENCP;
    if (j < DECP) {
      int k = j >> 8; int n = j & 255;
      decP[j] = (n < 128) ? dwk[k*128 + n] : dwv[k*128 + (n-128)];
    }
  }
}

// ---------------------------------------------------------------- embed
__global__ __launch_bounds__(256) void embed_k(
    const float* __restrict__ depot_xy, const float* __restrict__ node_xy,
    const float* __restrict__ node_demand,
    const float* __restrict__ wD, const float* __restrict__ bD,
    const float* __restrict__ wN, const float* __restrict__ bN,
    float* __restrict__ x)
{
  int t = blockIdx.x*256 + threadIdx.x;
  if (t >= Mtok*Ee) return;
  int e   = t & (Ee-1);
  int tok = t >> 7;
  int b   = tok / NT;
  int n   = tok - b*NT;
  float v;
  if (n == 0) {
    v = depot_xy[b*2+0]*wD[0*Ee+e] + depot_xy[b*2+1]*wD[1*Ee+e] + bD[e];
  } else {
    int nn = n - 1;
    float c0 = node_xy[(b*Nn + nn)*2 + 0];
    float c1 = node_xy[(b*Nn + nn)*2 + 1];
    float c2 = node_demand[b*Nn + nn];
    v = c0*wN[0*Ee+e] + c1*wN[1*Ee+e] + c2*wN[2*Ee+e] + bN[e];
  }
  x[(size_t)tok*Ee + e] = v;
}

// ---------------------------------------------------------------- GEMM (f32, proven)
__global__ __launch_bounds__(256) void gemm_k(
    const float* __restrict__ A, const float* __restrict__ W,
    const float* __restrict__ bias, const float* __restrict__ res,
    float* __restrict__ C, int M, int N, int K, int relu)
{
  __shared__ __align__(16) float As[2][16][68];
  __shared__ __align__(16) float Bs[2][16][68];
  int tid = threadIdx.x;
  int tx = tid & 15, ty = tid >> 4;
  int m0 = blockIdx.x * 64, n0 = blockIdx.y * 64;
  float acc[4][4];
  #pragma unroll
  for (int i=0;i<4;i++)
    #pragma unroll
    for (int j=0;j<4;j++) acc[i][j] = 0.f;

  int ar = tid >> 2;
  int ak = (tid & 3) << 2;
  int br = tid >> 4;
  int bc = (tid & 15) << 2;

  const float* Ap = A + (size_t)(m0 + ar)*K + ak;
  const float* Wp = W + (size_t)br*N + n0 + bc;
  bool aok = (m0 + ar) < M;

  float4 av = aok ? *(const float4*)(Ap) : make_float4(0.f,0.f,0.f,0.f);
  float4 wv = *(const float4*)(Wp);

  int nk = K >> 4;
  for (int t = 0; t < nk; ++t) {
    int cur = t & 1;
    As[cur][ak+0][ar] = av.x; As[cur][ak+1][ar] = av.y;
    As[cur][ak+2][ar] = av.z; As[cur][ak+3][ar] = av.w;
    *(float4*)(&Bs[cur][br][bc]) = wv;
    __syncthreads();
    if (t+1 < nk) {
      av = aok ? *(const float4*)(Ap + (t+1)*16) : make_float4(0.f,0.f,0.f,0.f);
      wv = *(const float4*)(Wp + (size_t)(t+1)*16*N);
    }
    #pragma unroll
    for (int k=0;k<16;k++){
      float4 a4 = *(const float4*)(&As[cur][k][ty*4]);
      float4 b4 = *(const float4*)(&Bs[cur][k][tx*4]);
      float avv[4] = {a4.x,a4.y,a4.z,a4.w};
      float bvv[4] = {b4.x,b4.y,b4.z,b4.w};
      #pragma unroll
      for (int i=0;i<4;i++)
        #pragma unroll
        for (int j=0;j<4;j++)
          acc[i][j] = fmaf(avv[i], bvv[j], acc[i][j]);
    }
  }

  float4 bv = make_float4(0.f,0.f,0.f,0.f);
  if (bias) bv = *(const float4*)(bias + n0 + tx*4);
  #pragma unroll
  for (int i=0;i<4;i++){
    int row = m0 + ty*4 + i;
    if (row >= M) continue;
    float4 o;
    o.x = acc[i][0] + bv.x; o.y = acc[i][1] + bv.y;
    o.z = acc[i][2] + bv.z; o.w = acc[i][3] + bv.w;
    if (relu){ o.x=fmaxf(o.x,0.f); o.y=fmaxf(o.y,0.f); o.z=fmaxf(o.z,0.f); o.w=fmaxf(o.w,0.f); }
    if (res){
      float4 rv = *(const float4*)(res + (size_t)row*N + n0 + tx*4);
      o.x += rv.x; o.y += rv.y; o.z += rv.z; o.w += rv.w;
    }
    *(float4*)(C + (size_t)row*N + n0 + tx*4) = o;
  }
}

// ---------------------------------------------------------------- attention
__device__ __forceinline__ float dot4(float4 a, float4 b){
  return fmaf(a.x,b.x, fmaf(a.y,b.y, fmaf(a.z,b.z, a.w*b.w)));
}

// encoder self-attention v7: 256 threads, 2 queries/thread, runtime KV-split,
// s-major block order; software-pipelined key loop (regs for key j while
// LDS reads for key j+1 are in flight).
__global__ __launch_bounds__(256, 1) void attn_enc_k(
    const float* __restrict__ QKV, float* __restrict__ part_o,
    float* __restrict__ part_l, int ksegsz)
{
  int blk = blockIdx.x;            // s*128 + bh
  int s  = blk >> 7;
  int bh = blk & 127;
  int h  = bh & (Hh-1);
  int b  = bh >> 3;
  int tid = threadIdx.x;
  int p0 = tid;
  int p1 = tid + 256;
  const int klo = s*ksegsz;
  int kseg = NT - klo; if (kseg > ksegsz) kseg = ksegsz;

  __shared__ __align__(16) float4 Ks[2][TJ][4];
  __shared__ __align__(16) float4 Vs[2][TJ][4];

  int row = (tid >> 2) & 31;
  int lc  = tid & 3;
  bool isV = tid >= 128;
  const int kvoff = isV ? 256 : 128;

  bool vbq = p1 < NT;

  const float4* qp0 = (const float4*)(QKV + ((size_t)(b*NT + p0))*384 + h*Dd);
  float4 qa0=qp0[0], qa1=qp0[1], qa2=qp0[2], qa3=qp0[3];
  float4 qb0,qb1,qb2,qb3;
  if (vbq) {
    const float4* qp1 = (const float4*)(QKV + ((size_t)(b*NT + p1))*384 + h*Dd);
    qb0=qp1[0]; qb1=qp1[1]; qb2=qp1[2]; qb3=qp1[3];
  } else {
    qb0=qb1=qb2=qb3=make_float4(0,0,0,0);
  }

  if (row < kseg) {
    float4 v = *((const float4*)(QKV + ((size_t)(b*NT + klo + row))*384 + kvoff + h*Dd) + lc);
    if (isV) Vs[0][row][lc] = v; else Ks[0][row][lc] = v;
  }
  __syncthreads();

  float lA = 0.f, lB = 0.f;
  float4 oA0=make_float4(0,0,0,0), oA1=oA0, oA2=oA0, oA3=oA0;
  float4 oB0=oA0, oB1=oA0, oB2=oA0, oB3=oA0;
  const int ntiles = (kseg + TJ - 1)/TJ;
  int buf = 0;

  for (int t = 0; t < ntiles; ++t) {
    int j0 = t*TJ;
    if (t+1 < ntiles) {
      int jj = j0 + TJ + row;
      if (jj < kseg) {
        float4 v = *((const float4*)(QKV + ((size_t)(b*NT + klo + jj))*384 + kvoff + h*Dd) + lc);
        if (isV) Vs[buf^1][row][lc] = v; else Ks[buf^1][row][lc] = v;
      }
    }
    int jend = kseg - j0; if (jend > TJ) jend = TJ;

    // --- software-pipelined key loop: regs for key jj, LDS reads for jj+1 in flight ---
    float4 ck0=Ks[buf][0][0], ck1=Ks[buf][0][1], ck2=Ks[buf][0][2], ck3=Ks[buf][0][3];
    float4 cv0=Vs[buf][0][0], cv1=Vs[buf][0][1], cv2=Vs[buf][0][2], cv3=Vs[buf][0][3];
    for (int jj = 0; jj < jend; ++jj) {
      int jn = (jj+1 < jend) ? jj+1 : jj;
      float4 nk0=Ks[buf][jn][0], nk1=Ks[buf][jn][1], nk2=Ks[buf][jn][2], nk3=Ks[buf][jn][3];
      float4 nv0=Vs[buf][jn][0], nv1=Vs[buf][jn][1], nv2=Vs[buf][jn][2], nv3=Vs[buf][jn][3];

      float sA = (dot4(qa0,ck0)+dot4(qa1,ck1)) + (dot4(qa2,ck2)+dot4(qa3,ck3));
      float sB = (dot4(qb0,ck0)+dot4(qb1,ck1)) + (dot4(qb2,ck2)+dot4(qb3,ck3));
      float wA = __expf(sA*0.25f);
      float wB = __expf(sB*0.25f);
      lA += wA; lB += wB;
      oA0.x=fmaf(wA,cv0.x,oA0.x); oA0.y=fmaf(wA,cv0.y,oA0.y); oA0.z=fmaf(wA,cv0.z,oA0.z); oA0.w=fmaf(wA,cv0.w,oA0.w);
      oA1.x=fmaf(wA,cv1.x,oA1.x); oA1.y=fmaf(wA,cv1.y,oA1.y); oA1.z=fmaf(wA,cv1.z,oA1.z); oA1.w=fmaf(wA,cv1.w,oA1.w);
      oA2.x=fmaf(wA,cv2.x,oA2.x); oA2.y=fmaf(wA,cv2.y,oA2.y); oA2.z=fmaf(wA,cv2.z,oA2.z); oA2.w=fmaf(wA,cv2.w,oA2.w);
      oA3.x=fmaf(wA,cv3.x,oA3.x); oA3.y=fmaf(wA,cv3.y,oA3.y); oA3.z=fmaf(wA,cv3.z,oA3.z); oA3.w=fmaf(wA,cv3.w,oA3.w);
      oB0.x=fmaf(wB,cv0.x,oB0.x); oB0.y=fmaf(wB,cv0.y,oB0.y); oB0.z=fmaf(wB,cv0.z,oB0.z); oB0.w=fmaf(wB,cv0.w,oB0.w);
      oB1.x=fmaf(wB,cv1.x,oB1.x); oB1.y=fmaf(wB,cv1.y,oB1.y); oB1.z=fmaf(wB,cv1.z,oB1.z); oB1.w=fmaf(wB,cv1.w,oB1.w);
      oB2.x=fmaf(wB,cv2.x,oB2.x); oB2.y=fmaf(wB,cv2.y,oB2.y); oB2.z=fmaf(wB,cv2.z,oB2.z); oB2.w=fmaf(wB,cv2.w,oB2.w);
      oB3.x=fmaf(wB,cv3.x,oB3.x); oB3.y=fmaf(wB,cv3.y,oB3.y); oB3.z=fmaf(wB,cv3.z,oB3.z); oB3.w=fmaf(wB,cv3.w,oB3.w);

      ck0=nk0; ck1=nk1; ck2=nk2; ck3=nk3;
      cv0=nv0; cv1=nv1; cv2=nv2; cv3=nv3;
    }
    __syncthreads();
    buf ^= 1;
  }

  size_t r0 = ((size_t)s*128 + bh)*NT + p0;
  float4* po0 = (float4*)(part_o + r0*16);
  po0[0]=oA0; po0[1]=oA1; po0[2]=oA2; po0[3]=oA3;
  part_l[r0] = lA;
  if (vbq) {
    size_t r1 = ((size_t)s*128 + bh)*NT + p1;
    float4* po1 = (float4*)(part_o + r1*16);
    po1[0]=oB0; po1[1]=oB1; po1[2]=oB2; po1[3]=oB3;
    part_l[r1] = lB;
  }
}

// combine nsplit partials (plain sums) -> O[b,q,h,d]
__global__ __launch_bounds__(256) void attn_comb_k(
    const float* __restrict__ part_o, const float* __restrict__ part_l,
    float* __restrict__ O, int nsplit)
{
  int t = blockIdx.x*256 + threadIdx.x;
  if (t >= 128*NT*16) return;
  int d  = t & 15;
  int rq = t >> 4;
  int q  = rq % NT;
  int bh = rq / NT;
  int h = bh & 7, b = bh >> 3;
  const size_t R = (size_t)128*NT;
  float L = 0.f, o = 0.f;
  for (int s=0;s<nsplit;s++){
    L += part_l[(size_t)s*R + rq];
    o += part_o[((size_t)s*R + rq)*16 + d];
  }
  O[((size_t)(b*NT + q))*Ee + h*Dd + d] = o / L;
}

// decoder cross-attention: LDS-staged broadcast, DSPLIT=16 segments of 32.
__global__ __launch_bounds__(128) void attn_dec_k(
    const float* __restrict__ Q, const float* __restrict__ KV,
    const float* __restrict__ mask,
    float* __restrict__ part_o, float* __restrict__ part_l)
{
  int blk = blockIdx.x;
  int s  = blk & (DSPLIT-1);
  int bh = blk >> 4;
  int h  = bh & (Hh-1);
  int b  = bh >> 3;
  int klo = s*DSEG;
  int kn  = NT - klo; if (kn > DSEG) kn = DSEG;

  __shared__ __align__(16) float4 Ks[DSEG][4];
  __shared__ __align__(16) float4 Vs[DSEG][4];

  int tid = threadIdx.x;
  for (int i = tid; i < kn*8; i += 128) {
    int row  = i >> 3;
    int q8   = i & 7;
    int quad = q8 & 3;
    int isv  = q8 >> 2;
    float4 v = *(const float4*)(KV + ((size_t)(b*NT + klo + row))*256 + isv*128 + h*Dd + quad*4);
    if (isv) Vs[row][quad] = v; else Ks[row][quad] = v;
  }
  __syncthreads();

  int p = tid;
  if (p >= Pp) return;
  int r = b*Pp + p;
  const float4* qp = (const float4*)(Q + (size_t)r*Ee + h*Dd);
  float4 qa=qp[0], qb=qp[1], qc=qp[2], qd=qp[3];
  const float* mrow = mask + (size_t)r*NT + klo;

  float l = 0.f;
  float4 o0=make_float4(0,0,0,0), o1=o0, o2=o0, o3=o0;
  for (int j=0;j<kn;++j){
    float sc = (dot4(qa,Ks[j][0])+dot4(qb,Ks[j][1])) + (dot4(qc,Ks[j][2])+dot4(qd,Ks[j][3]));
    float w = __expf(sc*0.25f + mrow[j]);
    l += w;
    float4 v0=Vs[j][0],v1=Vs[j][1],v2=Vs[j][2],v3=Vs[j][3];
    o0.x=fmaf(w,v0.x,o0.x); o0.y=fmaf(w,v0.y,o0.y); o0.z=fmaf(w,v0.z,o0.z); o0.w=fmaf(w,v0.w,o0.w);
    o1.x=fmaf(w,v1.x,o1.x); o1.y=fmaf(w,v1.y,o1.y); o1.z=fmaf(w,v1.z,o1.z); o1.w=fmaf(w,v1.w,o1.w);
    o2.x=fmaf(w,v2.x,o2.x); o2.y=fmaf(w,v2.y,o2.y); o2.z=fmaf(w,v2.z,o2.z); o2.w=fmaf(w,v2.w,o2.w);
    o3.x=fmaf(w,v3.x,o3.x); o3.y=fmaf(w,v3.y,o3.y); o3.z=fmaf(w,v3.z,o3.z); o3.w=fmaf(w,v3.w,o3.w);
  }

  size_t rb = ((size_t)s*PR + r)*Hh + h;
  float4* po = (float4*)(part_o + rb*16);
  po[0]=o0; po[1]=o1; po[2]=o2; po[3]=o3;
  part_l[rb] = l;
}

// ---------------------------------------------------------------- decoder small ops
__global__ __launch_bounds__(128) void decq_k(
    const float* __restrict__ x, const int* __restrict__ cur,
    const float* __restrict__ loadv, const float* __restrict__ Wq,
    float* __restrict__ q, float* __restrict__ encl)
{
  __shared__ float row[Ee];
  int r = blockIdx.x, e = threadIdx.x;
  int b = r / Pp;
  int node = cur[r];
  float xv = x[((size_t)(b*NT + node))*Ee + e];
  encl[(size_t)r*Ee + e] = xv;
  row[e] = xv;
  __syncthreads();
  float acc = 0.f;
  #pragma unroll 4
  for (int k=0;k<Ee;k++) acc = fmaf(row[k], Wq[k*128 + e], acc);
  acc = fmaf(loadv[r], Wq[Ee*128 + e], acc);
  q[(size_t)r*128 + e] = acc;
}

__global__ __launch_bounds__(128) void dec_comb_k(
    const float* __restrict__ dpart_o, const float* __restrict__ dpart_l,
    const float* __restrict__ W, const float* __restrict__ bias,
    const float* __restrict__ encl, const float* __restrict__ loadv,
    const float* __restrict__ capw, float* __restrict__ mh)
{
  __shared__ float row[Ee];
  int r = blockIdx.x, e = threadIdx.x;
  int h = e >> 4, d = e & 15;
  const size_t S = (size_t)PR*Hh;
  size_t rb = (size_t)r*Hh + h;
  float L = 0.f, o = 0.f;
  #pragma unroll
  for (int s=0;s<DSPLIT;s++){
    L += dpart_l[(size_t)s*S + rb];
    o += dpart_o[((size_t)s*S + rb)*16 + d];
  }
  row[e] = o / L;
  __syncthreads();
  float acc = 0.f;
  #pragma unroll 4
  for (int k=0;k<Ee;k++) acc = fmaf(row[k], W[k*Ee + e], acc);
  mh[(size_t)r*Ee + e] = acc + bias[e] + encl[(size_t)r*Ee + e] + loadv[r]*capw[e];
}

// ---------------------------------------------------------------- score via batched GEMM
__global__ __launch_bounds__(256) void xt_k(
    const float* __restrict__ x, float* __restrict__ xT)
{
  __shared__ float T[32][33];
  int n0 = blockIdx.x * 32;
  int k0 = blockIdx.y * 32;
  int b  = blockIdx.z;
  int t  = threadIdx.x;
  int row = t >> 3;
  int c4  = (t & 7) << 2;

  int n = n0 + row;
  float4 v = make_float4(0.f,0.f,0.f,0.f);
  if (n < NT) v = *(const float4*)(x + ((size_t)(b*NT + n))*Ee + k0 + c4);
  T[c4+0][row] = v.x; T[c4+1][row] = v.y; T[c4+2][row] = v.z; T[c4+3][row] = v.w;
  __syncthreads();

  const float SC = 0.08838834764831845f;
  float4 o;
  o.x = T[row][c4+0]*SC; o.y = T[row][c4+1]*SC;
  o.z = T[row][c4+2]*SC; o.w = T[row][c4+3]*SC;
  *(float4*)(xT + ((size_t)(b*Ee + k0 + row))*SNP + n0 + c4) = o;
}

__global__ __launch_bounds__(256) void score_gemm_k(
    const float* __restrict__ qref, const float* __restrict__ xT,
    float* __restrict__ score)
{
  __shared__ __align__(16) float As[2][16][68];
  __shared__ __align__(16) float Bs[2][16][68];
  int tid = threadIdx.x;
  int tx = tid & 15, ty = tid >> 4;
  int m0 = blockIdx.x * 64;
  int n0 = blockIdx.y * 64;
  int b  = blockIdx.z;

  const float* A = qref + (size_t)b*Pp*Ee;
  const float* W = xT   + (size_t)b*Ee*SNP;
  float*       C = score + (size_t)b*Pp*SNP;

  float acc[4][4];
  #pragma unroll
  for (int i=0;i<4;i++)
    #pragma unroll
    for (int j=0;j<4;j++) acc[i][j] = 0.f;

  int ar = tid >> 2;
  int ak = (tid & 3) << 2;
  int br = tid >> 4;
  int bc = (tid & 15) << 2;

  const float* Ap = A + (size_t)(m0 + ar)*Ee + ak;
  const float* Wp = W + (size_t)br*SNP + n0 + bc;
  bool aok = (m0 + ar) < Pp;

  float4 av = aok ? *(const float4*)(Ap) : make_float4(0.f,0.f,0.f,0.f);
  float4 wv = *(const float4*)(Wp);

  for (int t = 0; t < 8; ++t) {
    int cur = t & 1;
    As[cur][ak+0][ar] = av.x; As[cur][ak+1][ar] = av.y;
    As[cur][ak+2][ar] = av.z; As[cur][ak+3][ar] = av.w;
    *(float4*)(&Bs[cur][br][bc]) = wv;
    __syncthreads();
    if (t+1 < 8) {
      av = aok ? *(const float4*)(Ap + (t+1)*16) : make_float4(0.f,0.f,0.f,0.f);
      wv = *(const float4*)(Wp + (size_t)(t+1)*16*SNP);
    }
    #pragma unroll
    for (int k=0;k<16;k++){
      float4 a4 = *(const float4*)(&As[cur][k][ty*4]);
      float4 b4 = *(const float4*)(&Bs[cur][k][tx*4]);
      float avv[4] = {a4.x,a4.y,a4.z,a4.w};
      float bvv[4] = {b4.x,b4.y,b4.z,b4.w};
      #pragma unroll
      for (int i=0;i<4;i++)
        #pragma unroll
        for (int j=0;j<4;j++)
          acc[i][j] = fmaf(avv[i], bvv[j], acc[i][j]);
    }
    __syncthreads();
  }

  #pragma unroll
  for (int i=0;i<4;i++){
    int row = m0 + ty*4 + i;
    if (row >= Pp) continue;
    float4 o;
    o.x = acc[i][0]; o.y = acc[i][1]; o.z = acc[i][2]; o.w = acc[i][3];
    *(float4*)(C + (size_t)row*SNP + n0 + tx*4) = o;
  }
}

// ---------------------------------------------------------------- threefry noise
__device__ __forceinline__ unsigned rotl32(unsigned x, int r){ return (x<<r)|(x>>(32-r)); }

__device__ float tf_normal(unsigned idx)
{
  unsigned x0 = 0u;
  unsigned x1 = idx;
  const unsigned ks[3] = {0u, 42u, 0u ^ 42u ^ 0x1BD11BDAu};
  x0 += ks[0]; x1 += ks[1];
  const int rotA[4] = {13,15,26,6};
  const int rotB[4] = {17,29,16,24};
  #pragma unroll
  for (int i=0;i<5;i++){
    #pragma unroll
    for (int q=0;q<4;q++){
      int rr = (i&1) ? rotB[q] : rotA[q];
      x0 += x1; x1 = rotl32(x1, rr); x1 ^= x0;
    }
    x0 += ks[(i+1)%3];
    x1 += ks[(i+2)%3] + (unsigned)(i+1);
  }
  unsigned bits = x0 ^ x1;
  float f = __uint_as_float((bits >> 9) | 0x3f800000u) - 1.0f;
  const float lo = -0.99999994f;
  float u = f * 2.0f + lo;
  u = fmaxf(lo, u);
  float w = -log1pf(-u*u);
  float p;
  if (w < 5.0f) {
    w -= 2.5f;
    p = 2.81022636e-08f;
    p = fmaf(p, w, 3.43273939e-07f);
    p = fmaf(p, w, -3.5233877e-06f);
    p = fmaf(p, w, -4.39150654e-06f);
    p = fmaf(p, w, 0.00021858087f);
    p = fmaf(p, w, -0.00125372503f);
    p = fmaf(p, w, -0.00417768164f);
    p = fmaf(p, w, 0.246640727f);
    p = fmaf(p, w, 1.50140941f);
  } else {
    w = sqrtf(w) - 3.0f;
    p = -0.000200214257f;
    p = fmaf(p, w, 0.000100950558f);
    p = fmaf(p, w, 0.00134934322f);
    p = fmaf(p, w, -0.00367342844f);
    p = fmaf(p, w, 0.00573950773f);
    p = fmaf(p, w, -0.0076224613f);
    p = fmaf(p, w, 0.00943887047f);
    p = fmaf(p, w, 1.00167406f);
    p = fmaf(p, w, 2.83297682f);
  }
  return 1.4142135623730951f * (p * u);
}

// ---------------------------------------------------------------- finalize (f32)
__global__ __launch_bounds__(512) void final_k(
    const float* __restrict__ score, const float* __restrict__ cur_dist,
    const float* __restrict__ ninf, float* __restrict__ out)
{
  __shared__ float smn[8], smx[8], sm2[8], ss[8];
  const float NM = (float)(50.0/501.0);
  const float C1 = (float)(1.0 - 50.0/501.0);
  int r = blockIdx.x;
  int t = threadIdx.x;
  int wid = t >> 6, lane = t & 63;

  float cd = 0.f;
  float mn = 1e30f, mx = -1e30f;
  if (t < NT) { cd = cur_dist[(size_t)r*NT + t]; mn = cd; mx = cd; }
  #pragma unroll
  for (int off=32; off>=1; off>>=1){
    mn = fminf(mn, __shfl_xor(mn, off));
    mx = fmaxf(mx, __shfl_xor(mx, off));
  }
  if (lane == 0){ smn[wid] = mn; smx[wid] = mx; }
  __syncthreads();
  float dmin = smn[0], dmax = smx[0];
  #pragma unroll
  for (int i=1;i<8;i++){ dmin = fminf(dmin, smn[i]); dmax = fmaxf(dmax, smx[i]); }

  float sval = -1e30f;
  if (t < NT) {
    float nd = (cd - dmin) / (dmax - dmin + 1e-6f);
    float z  = tf_normal((unsigned)r*501u + (unsigned)t);
    float s  = score[(size_t)r*SNP + t] - C1*logf(nd + 1e-6f) + (z*0.2f + 0.5f)*NM;
    sval = 10.0f*tanhf(s) + ninf[(size_t)r*NT + t];
  }
  float mv = sval;
  #pragma unroll
  for (int off=32; off>=1; off>>=1) mv = fmaxf(mv, __shfl_xor(mv, off));
  if (lane == 0) sm2[wid] = mv;
  __syncthreads();
  float smax = sm2[0];
  #pragma unroll
  for (int i=1;i<8;i++) smax = fmaxf(smax, sm2[i]);

  float e = (t < NT) ? expf(sval - smax) : 0.f;
  float sv = e;
  #pragma unroll
  for (int off=32; off>=1; off>>=1) sv += __shfl_xor(sv, off);
  if (lane == 0) ss[wid] = sv;
  __syncthreads();
  float ssum = ss[0];
  #pragma unroll
  for (int i=1;i<8;i++) ssum += ss[i];

  if (t < NT) out[(size_t)r*NT + t] = e / ssum;
}

// ---------------------------------------------------------------- launch
extern "C" void kernel_launch(void* const* d_in, const int* in_sizes, int n_in,
                              void* d_out, int out_size, void* d_ws, size_t ws_size,
                              hipStream_t stream)
{
  (void)in_sizes; (void)n_in; (void)out_size;
  const float* depot_xy    = (const float*)d_in[0];
  const float* node_xy     = (const float*)d_in[1];
  const float* node_demand = (const float*)d_in[2];
  const float* loadv       = (const float*)d_in[3];
  const float* cur_dist    = (const float*)d_in[4];
  const float* ninf        = (const float*)d_in[5];
  const int*   cur_node    = (const int*)d_in[6];
  const float* emb_depot_w = (const float*)d_in[7];
  const float* emb_depot_b = (const float*)d_in[8];
  const float* emb_node_w  = (const float*)d_in[9];
  const float* emb_node_b  = (const float*)d_in[10];
  const float* enc_wq      = (const float*)d_in[11];
  const float* enc_wk      = (const float*)d_in[12];
  const float* enc_wv      = (const float*)d_in[13];
  const float* enc_comb_w  = (const float*)d_in[14];
  const float* enc_comb_b  = (const float*)d_in[15];
  const float* enc_ff1_w   = (const float*)d_in[16];
  const float* enc_ff1_b   = (const float*)d_in[17];
  const float* enc_ff2_w   = (const float*)d_in[18];
  const float* enc_ff2_b   = (const float*)d_in[19];
  const float* dec_wq_last = (const float*)d_in[20];
  const float* dec_wk      = (const float*)d_in[21];
  const float* dec_wv      = (const float*)d_in[22];
  const float* dec_comb_w  = (const float*)d_in[23];
  const float* dec_comb_b  = (const float*)d_in[24];
  const float* dec_cap_w   = (const float*)d_in[25];
  const float* dec_ff1_w   = (const float*)d_in[26];
  const float* dec_ff1_b   = (const float*)d_in[27];
  const float* dec_ff2_w   = (const float*)d_in[28];
  const float* dec_ff2_b   = (const float*)d_in[29];

  float* ws = (float*)d_ws;
  const size_t SZ = (size_t)Mtok*Ee;   // 1,026,048
  float* xb    = ws + 0*SZ;
  float* qkvb  = ws + 1*SZ;            // enc QKV [Mtok][384]; dec KV [Mtok][256]
  float* atb   = ws + 4*SZ;            // comb input; dec qref
  float* o1b   = ws + 5*SZ;            // part_l; comb out; score
  float* ffb   = ws + 6*SZ;            // FF scratch (4*SZ); part_o (SPLIT4); xT
  float* encPk = ws + 10*SZ;
  float* decPk = encPk + ENCP;
  float* ext   = decPk + DECP;         // extra region for SPLIT8 partials

  const size_t need8 = (size_t)(10*SZ + ENCP + DECP + 8*SZ) * sizeof(float);
  int ESPLIT, EKSEG;
  float* part_o;
  if (ws_size >= need8) { ESPLIT = 8; EKSEG = 63;  part_o = ext; }
  else                  { ESPLIT = 4; EKSEG = 126; part_o = ffb; }
  float* part_l  = o1b;
  float* dpart_o = ffb;
  float* dpart_l = o1b;
  float* encl  = qkvb + 2*SZ;
  float* qdec  = encl + 204800;
  float* mhb   = qdec + 204800;
  float* qrefb = atb;
  float* ffh2  = ffb;
  float* xTb   = ffb;
  float* scoreb= o1b;

  pack_k<<<(ENCP + DECP + 255)/256, 256, 0, stream>>>(
      enc_wq, enc_wk, enc_wv, dec_wk, dec_wv, encPk, decPk);

  embed_k<<<(Mtok*Ee + 255)/256, 256, 0, stream>>>(
      depot_xy, node_xy, node_demand, emb_depot_w, emb_depot_b,
      emb_node_w, emb_node_b, xb);

  dim3 gqkv((Mtok + 63)/64, 384/64);
  dim3 g128((Mtok + 63)/64, Ee/64);
  dim3 gff ((Mtok + 63)/64, Ff/64);
  const int gcomb = (128*NT*16 + 255)/256;
  for (int l = 0; l < Ll; ++l) {
    gemm_k<<<gqkv, 256, 0, stream>>>(xb, encPk + (size_t)l*128*384, nullptr, nullptr, qkvb, Mtok, 384, Ee, 0);
    attn_enc_k<<<ESPLIT*128, 256, 0, stream>>>(qkvb, part_o, part_l, EKSEG);
    attn_comb_k<<<gcomb, 256, 0, stream>>>(part_o, part_l, atb, ESPLIT);
    gemm_k<<<g128, 256, 0, stream>>>(atb, enc_comb_w + (size_t)l*Ee*Ee, enc_comb_b + l*Ee, xb, o1b, Mtok, Ee, Ee, 0);
    gemm_k<<<gff, 256, 0, stream>>>(o1b, enc_ff1_w + (size_t)l*Ee*Ff, enc_ff1_b + l*Ff, nullptr, ffb, Mtok, Ff, Ee, 1);
    gemm_k<<<g128, 256, 0, stream>>>(ffb, enc_ff2_w + (size_t)l*Ff*Ee, enc_ff2_b + l*Ee, o1b, xb, Mtok, Ee, Ff, 0);
  }

  // decoder
  dim3 gkv((Mtok + 63)/64, 256/64);
  gemm_k<<<gkv, 256, 0, stream>>>(xb, decPk, nullptr, nullptr, qkvb, Mtok, 256, Ee, 0);
  decq_k<<<PR, 128, 0, stream>>>(xb, cur_node, loadv, dec_wq_last, qdec, encl);
  attn_dec_k<<<Bb*Hh*DSPLIT, 128, 0, stream>>>(qdec, qkvb, ninf, dpart_o, dpart_l);
  dec_comb_k<<<PR, 128, 0, stream>>>(dpart_o, dpart_l, dec_comb_w, dec_comb_b, encl, loadv, dec_cap_w, mhb);
  dim3 gd1((PR + 63)/64, Ff/64);
  gemm_k<<<gd1, 256, 0, stream>>>(mhb, dec_ff1_w, dec_ff1_b, nullptr, ffh2, PR, Ff, Ee, 1);
  dim3 gd2((PR + 63)/64, Ee/64);
  gemm_k<<<gd2, 256, 0, stream>>>(ffh2, dec_ff2_w, dec_ff2_b, mhb, qrefb, PR, Ee, Ff, 0);
  dim3 gxt(16, 4, 16);
  xt_k<<<gxt, 256, 0, stream>>>(xb, xTb);
  dim3 gsc(2, 8, 16);
  score_gemm_k<<<gsc, 256, 0, stream>>>(qrefb, xTb, scoreb);
  final_k<<<PR, 512, 0, stream>>>(scoreb, cur_dist, ninf, (float*)d_out);
}